// Round 1
// baseline (2144.626 us; speedup 1.0000x reference)
//
#include <hip/hip_runtime.h>
#include <cstdint>
#include <cstddef>

// ---------------------------------------------------------------------------
// GCN forward: Z0 = relu(A @ (X W0)); Z1 = relu(A @ (Z0 Wh1));
//              out = softmax(A @ (Z1 W1), axis=-1)
// A given as COO edges (row, col, val); we build CSR on-device every call.
// ---------------------------------------------------------------------------

#define SCAN_B 1024

// ---------------- CSR construction ----------------

__global__ void count_rows_k(const int* __restrict__ row, int* __restrict__ deg, int E) {
    int e = blockIdx.x * blockDim.x + threadIdx.x;
    if (e < E) atomicAdd(&deg[row[e]], 1);
}

__global__ __launch_bounds__(SCAN_B) void scan1_k(const int* __restrict__ deg,
                                                  int* __restrict__ part,
                                                  int* __restrict__ bsum, int n) {
    __shared__ int buf[SCAN_B];
    int tid = threadIdx.x;
    int i = blockIdx.x * SCAN_B + tid;
    int v = (i < n) ? deg[i] : 0;
    buf[tid] = v;
    __syncthreads();
    for (int off = 1; off < SCAN_B; off <<= 1) {
        int y = (tid >= off) ? buf[tid - off] : 0;
        __syncthreads();
        buf[tid] += y;
        __syncthreads();
    }
    if (i < n) part[i] = buf[tid] - v;             // exclusive
    if (tid == SCAN_B - 1) bsum[blockIdx.x] = buf[tid];
}

__global__ __launch_bounds__(128) void scan2_k(int* __restrict__ bsum, int nb) {
    __shared__ int buf[128];
    int tid = threadIdx.x;
    int v = (tid < nb) ? bsum[tid] : 0;
    buf[tid] = v;
    __syncthreads();
    for (int off = 1; off < 128; off <<= 1) {
        int y = (tid >= off) ? buf[tid - off] : 0;
        __syncthreads();
        buf[tid] += y;
        __syncthreads();
    }
    if (tid < nb) bsum[tid] = buf[tid] - v;        // exclusive block offsets
}

__global__ __launch_bounds__(SCAN_B) void scan3_k(int* __restrict__ rowptr,
                                                  const int* __restrict__ bsum,
                                                  int* __restrict__ cursor, int n, int E) {
    int i = blockIdx.x * SCAN_B + threadIdx.x;
    if (i < n) {
        int v = rowptr[i] + bsum[blockIdx.x];
        rowptr[i] = v;
        cursor[i] = v;
    }
    if (i == 0) rowptr[n] = E;
}

__global__ void scatter_k(const int* __restrict__ row, const int* __restrict__ col,
                          const float* __restrict__ val, int* __restrict__ cursor,
                          int* __restrict__ scol, float* __restrict__ sval, int E) {
    int e = blockIdx.x * blockDim.x + threadIdx.x;
    if (e < E) {
        int r = row[e];
        int p = atomicAdd(&cursor[r], 1);
        scol[p] = col[e];
        sval[p] = val[e];
    }
}

// ---------------- dense GEMM: C[N,M] = A[N,K] * B[K,M], f32 ----------------
// 64x64 tile, BK=32, 256 threads, 4x4 micro-tile per thread.

template <int K>
__global__ __launch_bounds__(256) void gemm_tile_k(const float* __restrict__ A,
                                                   const float* __restrict__ B,
                                                   float* __restrict__ C, int N, int M) {
    __shared__ float As[32][64];   // [k][m] (transposed stage)
    __shared__ float Bs[32][64];   // [k][n]

    const int tid = threadIdx.x;
    const int tx = tid & 15;        // n quad
    const int ty = tid >> 4;        // m quad
    const int row0 = blockIdx.x * 64;
    const int col0 = blockIdx.y * 64;

    // global-load assignments
    const int lr  = tid >> 3;        // 0..31  (A row within tile)
    const int lk4 = (tid & 7) * 4;   // 0..28  (A k quad)
    const int bkr = tid >> 4;        // 0..15  (B k row)
    const int bn4 = (tid & 15) * 4;  // 0..60  (B n quad)

    float acc[4][4] = {};

    for (int k0 = 0; k0 < K; k0 += 32) {
#pragma unroll
        for (int h = 0; h < 2; ++h) {
            int r = lr + h * 32;
            int grow = row0 + r;
            float4 a = make_float4(0.f, 0.f, 0.f, 0.f);
            if (grow < N) a = *(const float4*)&A[(size_t)grow * K + k0 + lk4];
            As[lk4 + 0][r] = a.x;
            As[lk4 + 1][r] = a.y;
            As[lk4 + 2][r] = a.z;
            As[lk4 + 3][r] = a.w;
        }
#pragma unroll
        for (int h = 0; h < 2; ++h) {
            int k = bkr + h * 16;
            float4 b = *(const float4*)&B[(size_t)(k0 + k) * M + col0 + bn4];
            *(float4*)&Bs[k][bn4] = b;
        }
        __syncthreads();
#pragma unroll
        for (int k = 0; k < 32; ++k) {
            float4 a = *(const float4*)&As[k][ty * 4];
            float4 b = *(const float4*)&Bs[k][tx * 4];
            acc[0][0] = fmaf(a.x, b.x, acc[0][0]);
            acc[0][1] = fmaf(a.x, b.y, acc[0][1]);
            acc[0][2] = fmaf(a.x, b.z, acc[0][2]);
            acc[0][3] = fmaf(a.x, b.w, acc[0][3]);
            acc[1][0] = fmaf(a.y, b.x, acc[1][0]);
            acc[1][1] = fmaf(a.y, b.y, acc[1][1]);
            acc[1][2] = fmaf(a.y, b.z, acc[1][2]);
            acc[1][3] = fmaf(a.y, b.w, acc[1][3]);
            acc[2][0] = fmaf(a.z, b.x, acc[2][0]);
            acc[2][1] = fmaf(a.z, b.y, acc[2][1]);
            acc[2][2] = fmaf(a.z, b.z, acc[2][2]);
            acc[2][3] = fmaf(a.z, b.w, acc[2][3]);
            acc[3][0] = fmaf(a.w, b.x, acc[3][0]);
            acc[3][1] = fmaf(a.w, b.y, acc[3][1]);
            acc[3][2] = fmaf(a.w, b.z, acc[3][2]);
            acc[3][3] = fmaf(a.w, b.w, acc[3][3]);
        }
        __syncthreads();
    }

#pragma unroll
    for (int i = 0; i < 4; ++i) {
        int grow = row0 + ty * 4 + i;
        if (grow < N) {
            float4 o = make_float4(acc[i][0], acc[i][1], acc[i][2], acc[i][3]);
            *(float4*)&C[(size_t)grow * M + col0 + tx * 4] = o;
        }
    }
}

// ---------------- SpMM (CSR), one wave per row ----------------

// d = 256: lane owns float4; fused ReLU.
__global__ __launch_bounds__(256) void spmm_relu256_k(const int* __restrict__ rowptr,
                                                      const int* __restrict__ scol,
                                                      const float* __restrict__ sval,
                                                      const float* __restrict__ Z,
                                                      float* __restrict__ out, int N) {
    int row = blockIdx.x * 4 + (threadIdx.x >> 6);
    if (row >= N) return;
    int lane = threadIdx.x & 63;
    int s = rowptr[row], e = rowptr[row + 1];
    const float4* Zv = (const float4*)Z;   // row = 64 float4s
    float4 acc = make_float4(0.f, 0.f, 0.f, 0.f);
    for (int i = s; i < e; ++i) {
        int c = scol[i];
        float v = sval[i];
        float4 z = Zv[(size_t)c * 64 + lane];
        acc.x = fmaf(v, z.x, acc.x);
        acc.y = fmaf(v, z.y, acc.y);
        acc.z = fmaf(v, z.z, acc.z);
        acc.w = fmaf(v, z.w, acc.w);
    }
    float4 r = make_float4(fmaxf(acc.x, 0.f), fmaxf(acc.y, 0.f),
                           fmaxf(acc.z, 0.f), fmaxf(acc.w, 0.f));
    ((float4*)out)[(size_t)row * 64 + lane] = r;
}

// d = 64: lane owns one feature; fused row-softmax over 64 lanes.
__global__ __launch_bounds__(256) void spmm_softmax64_k(const int* __restrict__ rowptr,
                                                        const int* __restrict__ scol,
                                                        const float* __restrict__ sval,
                                                        const float* __restrict__ Z,
                                                        float* __restrict__ out, int N) {
    int row = blockIdx.x * 4 + (threadIdx.x >> 6);
    if (row >= N) return;
    int lane = threadIdx.x & 63;
    int s = rowptr[row], e = rowptr[row + 1];
    float acc = 0.f;
    for (int i = s; i < e; ++i) {
        acc = fmaf(sval[i], Z[(size_t)scol[i] * 64 + lane], acc);
    }
    float m = acc;
#pragma unroll
    for (int o = 32; o >= 1; o >>= 1) m = fmaxf(m, __shfl_xor(m, o));
    float p = __expf(acc - m);
    float ssum = p;
#pragma unroll
    for (int o = 32; o >= 1; o >>= 1) ssum += __shfl_xor(ssum, o);
    out[(size_t)row * 64 + lane] = p / ssum;
}

// ---------------------------------------------------------------------------

extern "C" void kernel_launch(void* const* d_in, const int* in_sizes, int n_in,
                              void* d_out, int out_size, void* d_ws, size_t ws_size,
                              hipStream_t stream) {
    const float* X        = (const float*)d_in[0];
    const int*   edge_row = (const int*)d_in[1];
    const int*   edge_col = (const int*)d_in[2];
    const float* edge_val = (const float*)d_in[3];
    const float* W0       = (const float*)d_in[4];
    const float* Wh1      = (const float*)d_in[5];
    const float* W1       = (const float*)d_in[6];

    const int C = 512, H = 256, F = 64;
    const int N = in_sizes[0] / C;     // 100000
    const int E = in_sizes[1];         // 3200000

    // workspace carve-up (256B aligned)
    size_t off = 0;
    auto alloc = [&](size_t bytes) -> void* {
        void* p = (char*)d_ws + off;
        off += (bytes + 255) & ~(size_t)255;
        return p;
    };
    float* bufA   = (float*)alloc((size_t)N * H * sizeof(float));   // matmul outs
    float* bufB   = (float*)alloc((size_t)N * H * sizeof(float));   // spmm outs
    int*   deg    = (int*)alloc((size_t)N * sizeof(int));
    int*   rowptr = (int*)alloc((size_t)(N + 1) * sizeof(int));
    int*   cursor = (int*)alloc((size_t)N * sizeof(int));
    int*   bsum   = (int*)alloc(128 * sizeof(int));
    int*   scol   = (int*)alloc((size_t)E * sizeof(int));
    float* sval   = (float*)alloc((size_t)E * sizeof(float));
    (void)ws_size;

    // ---- build CSR ----
    hipMemsetAsync(deg, 0, (size_t)N * sizeof(int), stream);
    count_rows_k<<<(E + 255) / 256, 256, 0, stream>>>(edge_row, deg, E);
    int nb = (N + SCAN_B - 1) / SCAN_B;          // 98 <= 128
    scan1_k<<<nb, SCAN_B, 0, stream>>>(deg, rowptr, bsum, N);
    scan2_k<<<1, 128, 0, stream>>>(bsum, nb);
    scan3_k<<<nb, SCAN_B, 0, stream>>>(rowptr, bsum, cursor, N, E);
    scatter_k<<<(E + 255) / 256, 256, 0, stream>>>(edge_row, edge_col, edge_val,
                                                   cursor, scol, sval, E);

    const int rowBlocks = (N + 63) / 64;         // 1563
    dim3 g1(rowBlocks, H / 64);                  // M = 256
    dim3 g3(rowBlocks, F / 64);                  // M = 64
    int spmmGrid = (N + 3) / 4;

    // ---- layer 0 ----
    gemm_tile_k<512><<<g1, 256, 0, stream>>>(X, W0, bufA, N, H);
    spmm_relu256_k<<<spmmGrid, 256, 0, stream>>>(rowptr, scol, sval, bufA, bufB, N);
    // ---- layer 1 ----
    gemm_tile_k<256><<<g1, 256, 0, stream>>>(bufB, Wh1, bufA, N, H);
    spmm_relu256_k<<<spmmGrid, 256, 0, stream>>>(rowptr, scol, sval, bufA, bufB, N);
    // ---- layer 2 ----
    gemm_tile_k<256><<<g3, 256, 0, stream>>>(bufB, W1, bufA, N, F);
    spmm_softmax64_k<<<spmmGrid, 256, 0, stream>>>(rowptr, scol, sval, bufA,
                                                   (float*)d_out, N);
}

// Round 2
// 1670.040 us; speedup vs baseline: 1.2842x; 1.2842x over previous
//
#include <hip/hip_runtime.h>
#include <cstdint>
#include <cstddef>

// ---------------------------------------------------------------------------
// GCN forward: Z0 = relu(A @ (X W0)); Z1 = relu(A @ (Z0 Wh1));
//              out = softmax(A @ (Z1 W1), axis=-1)
// CSR built on-device each call. Dense GEMMs use bf16 split-MFMA
// (C = Ahi*Bhi + Ahi*Blo + Alo*Bhi, truncation split, ~2^-16 rel error).
// ---------------------------------------------------------------------------

#define SCAN_B 1024

typedef __attribute__((ext_vector_type(8))) short short8_t;
typedef __attribute__((ext_vector_type(4))) short short4_t;
typedef __attribute__((ext_vector_type(4))) float f32x4;

__device__ __forceinline__ short bf16_hi(float x) {
    union { float f; unsigned u; } c; c.f = x;
    return (short)(c.u >> 16);
}
__device__ __forceinline__ float bf16_f32(short h) {
    union { float f; unsigned u; } c; c.u = ((unsigned)(unsigned short)h) << 16;
    return c.f;
}

// ---------------- CSR construction ----------------

__global__ void count_rows_k(const int* __restrict__ row, int* __restrict__ deg, int E) {
    int e = blockIdx.x * blockDim.x + threadIdx.x;
    if (e < E) atomicAdd(&deg[row[e]], 1);
}

__global__ __launch_bounds__(SCAN_B) void scan1_k(const int* __restrict__ deg,
                                                  int* __restrict__ part,
                                                  int* __restrict__ bsum, int n) {
    __shared__ int buf[SCAN_B];
    int tid = threadIdx.x;
    int i = blockIdx.x * SCAN_B + tid;
    int v = (i < n) ? deg[i] : 0;
    buf[tid] = v;
    __syncthreads();
    for (int off = 1; off < SCAN_B; off <<= 1) {
        int y = (tid >= off) ? buf[tid - off] : 0;
        __syncthreads();
        buf[tid] += y;
        __syncthreads();
    }
    if (i < n) part[i] = buf[tid] - v;             // exclusive
    if (tid == SCAN_B - 1) bsum[blockIdx.x] = buf[tid];
}

__global__ __launch_bounds__(128) void scan2_k(int* __restrict__ bsum, int nb) {
    __shared__ int buf[128];
    int tid = threadIdx.x;
    int v = (tid < nb) ? bsum[tid] : 0;
    buf[tid] = v;
    __syncthreads();
    for (int off = 1; off < 128; off <<= 1) {
        int y = (tid >= off) ? buf[tid - off] : 0;
        __syncthreads();
        buf[tid] += y;
        __syncthreads();
    }
    if (tid < nb) bsum[tid] = buf[tid] - v;        // exclusive block offsets
}

__global__ __launch_bounds__(SCAN_B) void scan3_k(int* __restrict__ rowptr,
                                                  const int* __restrict__ bsum,
                                                  int* __restrict__ cursor, int n, int E) {
    int i = blockIdx.x * SCAN_B + threadIdx.x;
    if (i < n) {
        int v = rowptr[i] + bsum[blockIdx.x];
        rowptr[i] = v;
        cursor[i] = v;
    }
    if (i == 0) rowptr[n] = E;
}

__global__ void scatter_k(const int* __restrict__ row, const int* __restrict__ col,
                          const float* __restrict__ val, int* __restrict__ cursor,
                          int* __restrict__ scol, float* __restrict__ sval, int E) {
    int e = blockIdx.x * blockDim.x + threadIdx.x;
    if (e < E) {
        int r = row[e];
        int p = atomicAdd(&cursor[r], 1);
        scol[p] = col[e];
        sval[p] = val[e];
    }
}

// ---------------- weight prep: split f32 W[K][M] -> bf16 Bt{hi,lo}[M][K] ----

__global__ void split_w_k(const float* __restrict__ W, short* __restrict__ Bthi,
                          short* __restrict__ Btlo, int K, int M) {
    int i = blockIdx.x * 256 + threadIdx.x;
    if (i >= K * M) return;
    int k = i / M, m = i - k * M;
    float x = W[i];
    short hi = bf16_hi(x);
    float r = x - bf16_f32(hi);
    short lo = bf16_hi(r);
    Bthi[(size_t)m * K + k] = hi;
    Btlo[(size_t)m * K + k] = lo;
}

// ---------------- split-MFMA GEMM: C[N,M] = A[N,K] * B[K,M] ----------------
// A is f32 (converted to bf16 hi/lo during LDS staging). B pre-split and
// pre-transposed to [M][K] bf16 (Bthi/Btlo). 128 x BN tile, BK=32, 4 waves.
// mfma_f32_16x16x32_bf16: A-frag row=lane&15, k=(lane>>4)*8+j;
// B-frag col=lane&15, same k; C/D col=lane&15, row=(lane>>4)*4+reg.

template <int K, int BN>
__global__ __launch_bounds__(256) void gemm_split_k(const float* __restrict__ A,
                                                    const short* __restrict__ Bthi,
                                                    const short* __restrict__ Btlo,
                                                    float* __restrict__ C, int N, int M) {
    constexpr int NF = BN / 32;                 // B frags per wave
    __shared__ short Ahi_s[128 * 32];
    __shared__ short Alo_s[128 * 32];
    __shared__ short Bhi_s[BN * 32];
    __shared__ short Blo_s[BN * 32];

    const int tid = threadIdx.x;
    const int lane = tid & 63;
    const int w = tid >> 6;
    const int wr = w >> 1, wc = w & 1;
    const int row0 = blockIdx.x * 128;
    const int col0 = blockIdx.y * BN;

    f32x4 acc[4][NF] = {};

    for (int k0 = 0; k0 < K; k0 += 32) {
        // ---- stage B tiles (pure copy, bf16) ----
#pragma unroll
        for (int h = 0; h < BN / 64; ++h) {
            int idx = h * 256 + tid;
            int cc = idx >> 2, q = idx & 3;
            size_t gb = (size_t)(col0 + cc) * K + k0 + q * 8;
            *(short8_t*)&Bhi_s[cc * 32 + q * 8] = *(const short8_t*)&Bthi[gb];
            *(short8_t*)&Blo_s[cc * 32 + q * 8] = *(const short8_t*)&Btlo[gb];
        }
        // ---- stage A tile (f32 -> hi/lo bf16) ----
#pragma unroll
        for (int h = 0; h < 4; ++h) {
            int idx = h * 256 + tid;
            int r = idx >> 3, q = idx & 7;
            int grow = row0 + r;
            float4 a = make_float4(0.f, 0.f, 0.f, 0.f);
            if (grow < N) a = *(const float4*)&A[(size_t)grow * K + k0 + q * 4];
            float ax[4] = {a.x, a.y, a.z, a.w};
            short4_t hi, lo;
#pragma unroll
            for (int j = 0; j < 4; ++j) {
                short h16 = bf16_hi(ax[j]);
                float rr = ax[j] - bf16_f32(h16);
                hi[j] = h16;
                lo[j] = bf16_hi(rr);
            }
            *(short4_t*)&Ahi_s[r * 32 + q * 4] = hi;
            *(short4_t*)&Alo_s[r * 32 + q * 4] = lo;
        }
        __syncthreads();

        // ---- fragments ----
        short8_t ah[4], al[4];
        const int kk = (lane >> 4) * 8;
#pragma unroll
        for (int m = 0; m < 4; ++m) {
            int r = wr * 64 + m * 16 + (lane & 15);
            ah[m] = *(const short8_t*)&Ahi_s[r * 32 + kk];
            al[m] = *(const short8_t*)&Alo_s[r * 32 + kk];
        }
        short8_t bh[NF], bl[NF];
#pragma unroll
        for (int n = 0; n < NF; ++n) {
            int cc = wc * (BN / 2) + n * 16 + (lane & 15);
            bh[n] = *(const short8_t*)&Bhi_s[cc * 32 + kk];
            bl[n] = *(const short8_t*)&Blo_s[cc * 32 + kk];
        }
#pragma unroll
        for (int m = 0; m < 4; ++m)
#pragma unroll
            for (int n = 0; n < NF; ++n) {
                acc[m][n] = __builtin_amdgcn_mfma_f32_16x16x32_bf16(ah[m], bh[n], acc[m][n], 0, 0, 0);
                acc[m][n] = __builtin_amdgcn_mfma_f32_16x16x32_bf16(ah[m], bl[n], acc[m][n], 0, 0, 0);
                acc[m][n] = __builtin_amdgcn_mfma_f32_16x16x32_bf16(al[m], bh[n], acc[m][n], 0, 0, 0);
            }
        __syncthreads();
    }

    // ---- epilogue ----
#pragma unroll
    for (int m = 0; m < 4; ++m)
#pragma unroll
        for (int n = 0; n < NF; ++n)
#pragma unroll
            for (int r = 0; r < 4; ++r) {
                int grow = row0 + wr * 64 + m * 16 + (lane >> 4) * 4 + r;
                int gcol = col0 + wc * (BN / 2) + n * 16 + (lane & 15);
                if (grow < N) C[(size_t)grow * M + gcol] = acc[m][n][r];
            }
}

// ---------------- SpMM (CSR), one wave per row, 4x unrolled gathers --------

__global__ __launch_bounds__(256) void spmm_relu256_k(const int* __restrict__ rowptr,
                                                      const int* __restrict__ scol,
                                                      const float* __restrict__ sval,
                                                      const float* __restrict__ Z,
                                                      float* __restrict__ out, int N) {
    int row = blockIdx.x * 4 + (threadIdx.x >> 6);
    if (row >= N) return;
    int lane = threadIdx.x & 63;
    int s = rowptr[row], e = rowptr[row + 1];
    const float4* Zv = (const float4*)Z;   // row = 64 float4s
    float4 acc = make_float4(0.f, 0.f, 0.f, 0.f);
    int i = s;
    for (; i + 4 <= e; i += 4) {
        int c0 = scol[i], c1 = scol[i + 1], c2 = scol[i + 2], c3 = scol[i + 3];
        float v0 = sval[i], v1 = sval[i + 1], v2 = sval[i + 2], v3 = sval[i + 3];
        float4 z0 = Zv[(size_t)c0 * 64 + lane];
        float4 z1 = Zv[(size_t)c1 * 64 + lane];
        float4 z2 = Zv[(size_t)c2 * 64 + lane];
        float4 z3 = Zv[(size_t)c3 * 64 + lane];
        acc.x = fmaf(v0, z0.x, acc.x); acc.y = fmaf(v0, z0.y, acc.y);
        acc.z = fmaf(v0, z0.z, acc.z); acc.w = fmaf(v0, z0.w, acc.w);
        acc.x = fmaf(v1, z1.x, acc.x); acc.y = fmaf(v1, z1.y, acc.y);
        acc.z = fmaf(v1, z1.z, acc.z); acc.w = fmaf(v1, z1.w, acc.w);
        acc.x = fmaf(v2, z2.x, acc.x); acc.y = fmaf(v2, z2.y, acc.y);
        acc.z = fmaf(v2, z2.z, acc.z); acc.w = fmaf(v2, z2.w, acc.w);
        acc.x = fmaf(v3, z3.x, acc.x); acc.y = fmaf(v3, z3.y, acc.y);
        acc.z = fmaf(v3, z3.z, acc.z); acc.w = fmaf(v3, z3.w, acc.w);
    }
    for (; i < e; ++i) {
        int c = scol[i];
        float v = sval[i];
        float4 z = Zv[(size_t)c * 64 + lane];
        acc.x = fmaf(v, z.x, acc.x); acc.y = fmaf(v, z.y, acc.y);
        acc.z = fmaf(v, z.z, acc.z); acc.w = fmaf(v, z.w, acc.w);
    }
    float4 r = make_float4(fmaxf(acc.x, 0.f), fmaxf(acc.y, 0.f),
                           fmaxf(acc.z, 0.f), fmaxf(acc.w, 0.f));
    ((float4*)out)[(size_t)row * 64 + lane] = r;
}

__global__ __launch_bounds__(256) void spmm_softmax64_k(const int* __restrict__ rowptr,
                                                        const int* __restrict__ scol,
                                                        const float* __restrict__ sval,
                                                        const float* __restrict__ Z,
                                                        float* __restrict__ out, int N) {
    int row = blockIdx.x * 4 + (threadIdx.x >> 6);
    if (row >= N) return;
    int lane = threadIdx.x & 63;
    int s = rowptr[row], e = rowptr[row + 1];
    float acc = 0.f;
    int i = s;
    for (; i + 4 <= e; i += 4) {
        int c0 = scol[i], c1 = scol[i + 1], c2 = scol[i + 2], c3 = scol[i + 3];
        float v0 = sval[i], v1 = sval[i + 1], v2 = sval[i + 2], v3 = sval[i + 3];
        float z0 = Z[(size_t)c0 * 64 + lane];
        float z1 = Z[(size_t)c1 * 64 + lane];
        float z2 = Z[(size_t)c2 * 64 + lane];
        float z3 = Z[(size_t)c3 * 64 + lane];
        acc = fmaf(v0, z0, acc);
        acc = fmaf(v1, z1, acc);
        acc = fmaf(v2, z2, acc);
        acc = fmaf(v3, z3, acc);
    }
    for (; i < e; ++i) acc = fmaf(sval[i], Z[(size_t)scol[i] * 64 + lane], acc);
    float m = acc;
#pragma unroll
    for (int o = 32; o >= 1; o >>= 1) m = fmaxf(m, __shfl_xor(m, o));
    float p = __expf(acc - m);
    float ssum = p;
#pragma unroll
    for (int o = 32; o >= 1; o >>= 1) ssum += __shfl_xor(ssum, o);
    out[(size_t)row * 64 + lane] = p / ssum;
}

// ---------------------------------------------------------------------------

extern "C" void kernel_launch(void* const* d_in, const int* in_sizes, int n_in,
                              void* d_out, int out_size, void* d_ws, size_t ws_size,
                              hipStream_t stream) {
    const float* X        = (const float*)d_in[0];
    const int*   edge_row = (const int*)d_in[1];
    const int*   edge_col = (const int*)d_in[2];
    const float* edge_val = (const float*)d_in[3];
    const float* W0       = (const float*)d_in[4];
    const float* Wh1      = (const float*)d_in[5];
    const float* W1       = (const float*)d_in[6];

    const int C = 512, H = 256, F = 64;
    const int N = in_sizes[0] / C;     // 100000
    const int E = in_sizes[1];         // 3200000

    size_t off = 0;
    auto alloc = [&](size_t bytes) -> void* {
        void* p = (char*)d_ws + off;
        off += (bytes + 255) & ~(size_t)255;
        return p;
    };
    float* bufA   = (float*)alloc((size_t)N * H * sizeof(float));   // GEMM outs
    float* bufB   = (float*)alloc((size_t)N * H * sizeof(float));   // SpMM outs
    int*   deg    = (int*)alloc((size_t)N * sizeof(int));
    int*   rowptr = (int*)alloc((size_t)(N + 1) * sizeof(int));
    int*   cursor = (int*)alloc((size_t)N * sizeof(int));
    int*   bsum   = (int*)alloc(128 * sizeof(int));
    int*   scol   = (int*)alloc((size_t)E * sizeof(int));
    float* sval   = (float*)alloc((size_t)E * sizeof(float));
    short* Bt0hi  = (short*)alloc((size_t)C * H * sizeof(short));
    short* Bt0lo  = (short*)alloc((size_t)C * H * sizeof(short));
    short* Bt1hi  = (short*)alloc((size_t)H * H * sizeof(short));
    short* Bt1lo  = (short*)alloc((size_t)H * H * sizeof(short));
    short* Bt2hi  = (short*)alloc((size_t)H * F * sizeof(short));
    short* Bt2lo  = (short*)alloc((size_t)H * F * sizeof(short));
    (void)ws_size;

    // ---- build CSR ----
    hipMemsetAsync(deg, 0, (size_t)N * sizeof(int), stream);
    count_rows_k<<<(E + 255) / 256, 256, 0, stream>>>(edge_row, deg, E);
    int nb = (N + SCAN_B - 1) / SCAN_B;          // 98 <= 128
    scan1_k<<<nb, SCAN_B, 0, stream>>>(deg, rowptr, bsum, N);
    scan2_k<<<1, 128, 0, stream>>>(bsum, nb);
    scan3_k<<<nb, SCAN_B, 0, stream>>>(rowptr, bsum, cursor, N, E);
    scatter_k<<<(E + 255) / 256, 256, 0, stream>>>(edge_row, edge_col, edge_val,
                                                   cursor, scol, sval, E);

    // ---- prep weights (split + transpose) ----
    split_w_k<<<(C * H + 255) / 256, 256, 0, stream>>>(W0, Bt0hi, Bt0lo, C, H);
    split_w_k<<<(H * H + 255) / 256, 256, 0, stream>>>(Wh1, Bt1hi, Bt1lo, H, H);
    split_w_k<<<(H * F + 255) / 256, 256, 0, stream>>>(W1, Bt2hi, Bt2lo, H, F);

    const int gx = (N + 127) / 128;              // 782
    int spmmGrid = (N + 3) / 4;

    // ---- layer 0 ----
    gemm_split_k<512, 128><<<dim3(gx, 2), 256, 0, stream>>>(X, Bt0hi, Bt0lo, bufA, N, H);
    spmm_relu256_k<<<spmmGrid, 256, 0, stream>>>(rowptr, scol, sval, bufA, bufB, N);
    // ---- layer 1 ----
    gemm_split_k<256, 128><<<dim3(gx, 2), 256, 0, stream>>>(bufB, Bt1hi, Bt1lo, bufA, N, H);
    spmm_relu256_k<<<spmmGrid, 256, 0, stream>>>(rowptr, scol, sval, bufA, bufB, N);
    // ---- layer 2 ----
    gemm_split_k<256, 64><<<dim3(gx, 1), 256, 0, stream>>>(bufB, Bt2hi, Bt2lo, bufA, N, F);
    spmm_softmax64_k<<<spmmGrid, 256, 0, stream>>>(rowptr, scol, sval, bufA,
                                                   (float*)d_out, N);
}

// Round 3
// 1647.754 us; speedup vs baseline: 1.3015x; 1.0135x over previous
//
#include <hip/hip_runtime.h>
#include <cstdint>
#include <cstddef>

// ---------------------------------------------------------------------------
// GCN forward. CSR built on-device. SpMM gathers per-row-int16-quantized Z
// (halves VMEM line traffic; error ~2^-15 relative to rowmax, negligible).
// Dense GEMMs: bf16 split-MFMA (3-term). Layers 1-2 consume pre-split bf16
// hi/lo A-planes written by the SpMM epilogue, staged via global_load_lds.
// ---------------------------------------------------------------------------

#define SCAN_B 1024

typedef __attribute__((ext_vector_type(8))) short short8_t;
typedef __attribute__((ext_vector_type(4))) short short4_t;
typedef __attribute__((ext_vector_type(4))) float f32x4;

__device__ __forceinline__ short bf16_hi(float x) {
    union { float f; unsigned u; } c; c.f = x;
    return (short)(c.u >> 16);
}
__device__ __forceinline__ float bf16_f32(short h) {
    union { float f; unsigned u; } c; c.u = ((unsigned)(unsigned short)h) << 16;
    return c.f;
}

__device__ __forceinline__ void gload_lds16(const void* g, void* l) {
    __builtin_amdgcn_global_load_lds(
        (const __attribute__((address_space(1))) void*)g,
        (__attribute__((address_space(3))) void*)l, 16, 0, 0);
}

// ---------------- CSR construction ----------------

__global__ void count_rows_k(const int* __restrict__ row, int* __restrict__ deg, int E) {
    int e = blockIdx.x * blockDim.x + threadIdx.x;
    if (e < E) atomicAdd(&deg[row[e]], 1);
}

__global__ __launch_bounds__(SCAN_B) void scan1_k(const int* __restrict__ deg,
                                                  int* __restrict__ part,
                                                  int* __restrict__ bsum, int n) {
    __shared__ int buf[SCAN_B];
    int tid = threadIdx.x;
    int i = blockIdx.x * SCAN_B + tid;
    int v = (i < n) ? deg[i] : 0;
    buf[tid] = v;
    __syncthreads();
    for (int off = 1; off < SCAN_B; off <<= 1) {
        int y = (tid >= off) ? buf[tid - off] : 0;
        __syncthreads();
        buf[tid] += y;
        __syncthreads();
    }
    if (i < n) part[i] = buf[tid] - v;
    if (tid == SCAN_B - 1) bsum[blockIdx.x] = buf[tid];
}

__global__ __launch_bounds__(128) void scan2_k(int* __restrict__ bsum, int nb) {
    __shared__ int buf[128];
    int tid = threadIdx.x;
    int v = (tid < nb) ? bsum[tid] : 0;
    buf[tid] = v;
    __syncthreads();
    for (int off = 1; off < 128; off <<= 1) {
        int y = (tid >= off) ? buf[tid - off] : 0;
        __syncthreads();
        buf[tid] += y;
        __syncthreads();
    }
    if (tid < nb) bsum[tid] = buf[tid] - v;
}

__global__ __launch_bounds__(SCAN_B) void scan3_k(int* __restrict__ rowptr,
                                                  const int* __restrict__ bsum,
                                                  int* __restrict__ cursor, int n, int E) {
    int i = blockIdx.x * SCAN_B + threadIdx.x;
    if (i < n) {
        int v = rowptr[i] + bsum[blockIdx.x];
        rowptr[i] = v;
        cursor[i] = v;
    }
    if (i == 0) rowptr[n] = E;
}

__global__ void scatter_k(const int* __restrict__ row, const int* __restrict__ col,
                          const float* __restrict__ val, int* __restrict__ cursor,
                          int* __restrict__ scol, float* __restrict__ sval, int E) {
    int e = blockIdx.x * blockDim.x + threadIdx.x;
    if (e < E) {
        int r = row[e];
        int p = atomicAdd(&cursor[r], 1);
        scol[p] = col[e];
        sval[p] = val[e];
    }
}

// ---------------- weight prep: split f32 W[K][M] -> bf16 Bt{hi,lo}[M][K] ----

__global__ void split_w_k(const float* __restrict__ W, short* __restrict__ Bthi,
                          short* __restrict__ Btlo, int K, int M) {
    int i = blockIdx.x * 256 + threadIdx.x;
    if (i >= K * M) return;
    int k = i / M, m = i - k * M;
    float x = W[i];
    short hi = bf16_hi(x);
    float r = x - bf16_f32(hi);
    short lo = bf16_hi(r);
    Bthi[(size_t)m * K + k] = hi;
    Btlo[(size_t)m * K + k] = lo;
}

// ---------------- per-row int16 quantization of Z[N][D] ----------------

template <int D>
__global__ __launch_bounds__(256) void quant_rows_k(const float* __restrict__ Z,
                                                    short* __restrict__ Q,
                                                    float* __restrict__ scl, int N) {
    int row = blockIdx.x * 4 + (threadIdx.x >> 6);
    if (row >= N) return;
    int lane = threadIdx.x & 63;
    if constexpr (D == 256) {
        float4 v = ((const float4*)Z)[(size_t)row * 64 + lane];
        float m = fmaxf(fmaxf(fabsf(v.x), fabsf(v.y)), fmaxf(fabsf(v.z), fabsf(v.w)));
#pragma unroll
        for (int o = 32; o >= 1; o >>= 1) m = fmaxf(m, __shfl_xor(m, o));
        float inv = (m > 0.f) ? 32767.f / m : 0.f;
        short4_t q;
        q[0] = (short)rintf(v.x * inv);
        q[1] = (short)rintf(v.y * inv);
        q[2] = (short)rintf(v.z * inv);
        q[3] = (short)rintf(v.w * inv);
        ((short4_t*)Q)[(size_t)row * 64 + lane] = q;
        if (lane == 0) scl[row] = m * (1.f / 32767.f);
    } else {  // D == 64
        float v = Z[(size_t)row * 64 + lane];
        float m = fabsf(v);
#pragma unroll
        for (int o = 32; o >= 1; o >>= 1) m = fmaxf(m, __shfl_xor(m, o));
        float inv = (m > 0.f) ? 32767.f / m : 0.f;
        Q[(size_t)row * 64 + lane] = (short)rintf(v * inv);
        if (lane == 0) scl[row] = m * (1.f / 32767.f);
    }
}

// ---------------- GEMM A: layer 0 (f32 A, in-kernel split) ----------------
// 128x128 tile, BK=32, 4 waves; reg-staged, per-lane guarded A loads.

template <int K, int BN>
__global__ __launch_bounds__(256) void gemm_split_k(const float* __restrict__ A,
                                                    const short* __restrict__ Bthi,
                                                    const short* __restrict__ Btlo,
                                                    float* __restrict__ C, int N, int M) {
    constexpr int NF = BN / 32;
    __shared__ short Ahi_s[128 * 32];
    __shared__ short Alo_s[128 * 32];
    __shared__ short Bhi_s[BN * 32];
    __shared__ short Blo_s[BN * 32];

    const int tid = threadIdx.x;
    const int lane = tid & 63;
    const int w = tid >> 6;
    const int wr = w >> 1, wc = w & 1;
    const int row0 = blockIdx.x * 128;
    const int col0 = blockIdx.y * BN;

    f32x4 acc[4][NF] = {};

    for (int k0 = 0; k0 < K; k0 += 32) {
#pragma unroll
        for (int h = 0; h < BN / 64; ++h) {
            int idx = h * 256 + tid;
            int cc = idx >> 2, q = idx & 3;
            size_t gb = (size_t)(col0 + cc) * K + k0 + q * 8;
            *(short8_t*)&Bhi_s[cc * 32 + q * 8] = *(const short8_t*)&Bthi[gb];
            *(short8_t*)&Blo_s[cc * 32 + q * 8] = *(const short8_t*)&Btlo[gb];
        }
#pragma unroll
        for (int h = 0; h < 4; ++h) {
            int idx = h * 256 + tid;
            int r = idx >> 3, q = idx & 7;
            int grow = row0 + r;
            float4 a = make_float4(0.f, 0.f, 0.f, 0.f);
            if (grow < N) a = *(const float4*)&A[(size_t)grow * K + k0 + q * 4];
            float ax[4] = {a.x, a.y, a.z, a.w};
            short4_t hi, lo;
#pragma unroll
            for (int j = 0; j < 4; ++j) {
                short h16 = bf16_hi(ax[j]);
                float rr = ax[j] - bf16_f32(h16);
                hi[j] = h16;
                lo[j] = bf16_hi(rr);
            }
            *(short4_t*)&Ahi_s[r * 32 + q * 4] = hi;
            *(short4_t*)&Alo_s[r * 32 + q * 4] = lo;
        }
        __syncthreads();

        short8_t ah[4], al[4];
        const int kk = (lane >> 4) * 8;
#pragma unroll
        for (int m = 0; m < 4; ++m) {
            int r = wr * 64 + m * 16 + (lane & 15);
            ah[m] = *(const short8_t*)&Ahi_s[r * 32 + kk];
            al[m] = *(const short8_t*)&Alo_s[r * 32 + kk];
        }
        short8_t bh[NF], bl[NF];
#pragma unroll
        for (int n = 0; n < NF; ++n) {
            int cc = wc * (BN / 2) + n * 16 + (lane & 15);
            bh[n] = *(const short8_t*)&Bhi_s[cc * 32 + kk];
            bl[n] = *(const short8_t*)&Blo_s[cc * 32 + kk];
        }
#pragma unroll
        for (int m = 0; m < 4; ++m)
#pragma unroll
            for (int n = 0; n < NF; ++n) {
                acc[m][n] = __builtin_amdgcn_mfma_f32_16x16x32_bf16(ah[m], bh[n], acc[m][n], 0, 0, 0);
                acc[m][n] = __builtin_amdgcn_mfma_f32_16x16x32_bf16(ah[m], bl[n], acc[m][n], 0, 0, 0);
                acc[m][n] = __builtin_amdgcn_mfma_f32_16x16x32_bf16(al[m], bh[n], acc[m][n], 0, 0, 0);
            }
        __syncthreads();
    }

#pragma unroll
    for (int m = 0; m < 4; ++m)
#pragma unroll
        for (int n = 0; n < NF; ++n)
#pragma unroll
            for (int r = 0; r < 4; ++r) {
                int grow = row0 + wr * 64 + m * 16 + (lane >> 4) * 4 + r;
                int gcol = col0 + wc * (BN / 2) + n * 16 + (lane & 15);
                if (grow < N) C[(size_t)grow * M + gcol] = acc[m][n][r];
            }
}

// ---------------- GEMM B: layers 1-2 (pre-split bf16 A planes) ----------
// Same tile/wave layout; staging via global_load_lds (16B, linear LDS).
// NOTE: may overread A planes by up to 96 rows — keep live buffers after them.

template <int K, int BN>
__global__ __launch_bounds__(256) void gemm_pre_k(const short* __restrict__ Ahi,
                                                  const short* __restrict__ Alo,
                                                  const short* __restrict__ Bthi,
                                                  const short* __restrict__ Btlo,
                                                  float* __restrict__ C, int N, int M) {
    constexpr int NF = BN / 32;
    __shared__ short Ahi_s[128 * 32];
    __shared__ short Alo_s[128 * 32];
    __shared__ short Bhi_s[BN * 32];
    __shared__ short Blo_s[BN * 32];

    const int tid = threadIdx.x;
    const int lane = tid & 63;
    const int w = tid >> 6;
    const int wr = w >> 1, wc = w & 1;
    const int row0 = blockIdx.x * 128;
    const int col0 = blockIdx.y * BN;

    f32x4 acc[4][NF] = {};

    // per-lane source offsets within a 16-row (1 KiB) chunk
    const int crow = lane >> 2;          // 0..15
    const int ckq  = (lane & 3) * 8;     // 0,8,16,24 (bf16)

    for (int k0 = 0; k0 < K; k0 += 32) {
        // A planes: 8 chunks of 16 rows each
        for (int ch = w; ch < 8; ch += 4) {
            size_t ga = (size_t)(row0 + ch * 16 + crow) * K + k0 + ckq;
            gload_lds16(&Ahi[ga], &Ahi_s[ch * 512]);
            gload_lds16(&Alo[ga], &Alo_s[ch * 512]);
        }
        // B planes: BN/16 chunks
        for (int ch = w; ch < BN / 16; ch += 4) {
            size_t gb = (size_t)(col0 + ch * 16 + crow) * K + k0 + ckq;
            gload_lds16(&Bthi[gb], &Bhi_s[ch * 512]);
            gload_lds16(&Btlo[gb], &Blo_s[ch * 512]);
        }
        __syncthreads();

        short8_t ah[4], al[4];
        const int kk = (lane >> 4) * 8;
#pragma unroll
        for (int m = 0; m < 4; ++m) {
            int r = wr * 64 + m * 16 + (lane & 15);
            ah[m] = *(const short8_t*)&Ahi_s[r * 32 + kk];
            al[m] = *(const short8_t*)&Alo_s[r * 32 + kk];
        }
        short8_t bh[NF], bl[NF];
#pragma unroll
        for (int n = 0; n < NF; ++n) {
            int cc = wc * (BN / 2) + n * 16 + (lane & 15);
            bh[n] = *(const short8_t*)&Bhi_s[cc * 32 + kk];
            bl[n] = *(const short8_t*)&Blo_s[cc * 32 + kk];
        }
#pragma unroll
        for (int m = 0; m < 4; ++m)
#pragma unroll
            for (int n = 0; n < NF; ++n) {
                acc[m][n] = __builtin_amdgcn_mfma_f32_16x16x32_bf16(ah[m], bh[n], acc[m][n], 0, 0, 0);
                acc[m][n] = __builtin_amdgcn_mfma_f32_16x16x32_bf16(ah[m], bl[n], acc[m][n], 0, 0, 0);
                acc[m][n] = __builtin_amdgcn_mfma_f32_16x16x32_bf16(al[m], bh[n], acc[m][n], 0, 0, 0);
            }
        __syncthreads();
    }

#pragma unroll
    for (int m = 0; m < 4; ++m)
#pragma unroll
        for (int n = 0; n < NF; ++n)
#pragma unroll
            for (int r = 0; r < 4; ++r) {
                int grow = row0 + wr * 64 + m * 16 + (lane >> 4) * 4 + r;
                int gcol = col0 + wc * (BN / 2) + n * 16 + (lane & 15);
                if (grow < N) C[(size_t)grow * M + gcol] = acc[m][n][r];
            }
}

// ---------------- SpMM (CSR), one wave per row, int16 gathers ----------

// d=256: gather short4 + per-source-row scale; epilogue relu + bf16 hi/lo split.
__global__ __launch_bounds__(256) void spmm_agg256_k(const int* __restrict__ rowptr,
                                                     const int* __restrict__ scol,
                                                     const float* __restrict__ sval,
                                                     const short* __restrict__ Q,
                                                     const float* __restrict__ scl,
                                                     short* __restrict__ Zhi,
                                                     short* __restrict__ Zlo, int N) {
    int row = blockIdx.x * 4 + (threadIdx.x >> 6);
    if (row >= N) return;
    int lane = threadIdx.x & 63;
    int s = rowptr[row], e = rowptr[row + 1];
    const short4_t* Qv = (const short4_t*)Q;
    f32x4 acc = {0.f, 0.f, 0.f, 0.f};
    for (int i = s; i < e; ++i) {
        int c = scol[i];
        float wv = sval[i] * scl[c];
        short4_t q = Qv[(size_t)c * 64 + lane];
        acc[0] = fmaf(wv, (float)q[0], acc[0]);
        acc[1] = fmaf(wv, (float)q[1], acc[1]);
        acc[2] = fmaf(wv, (float)q[2], acc[2]);
        acc[3] = fmaf(wv, (float)q[3], acc[3]);
    }
    short4_t hi, lo;
#pragma unroll
    for (int j = 0; j < 4; ++j) {
        float r = fmaxf(acc[j], 0.f);
        short h = bf16_hi(r);
        hi[j] = h;
        lo[j] = bf16_hi(r - bf16_f32(h));
    }
    ((short4_t*)Zhi)[(size_t)row * 64 + lane] = hi;
    ((short4_t*)Zlo)[(size_t)row * 64 + lane] = lo;
}

// d=64: gather 1 short + scale; fused row-softmax.
__global__ __launch_bounds__(256) void spmm_softmax64_k(const int* __restrict__ rowptr,
                                                        const int* __restrict__ scol,
                                                        const float* __restrict__ sval,
                                                        const short* __restrict__ Q,
                                                        const float* __restrict__ scl,
                                                        float* __restrict__ out, int N) {
    int row = blockIdx.x * 4 + (threadIdx.x >> 6);
    if (row >= N) return;
    int lane = threadIdx.x & 63;
    int s = rowptr[row], e = rowptr[row + 1];
    float acc = 0.f;
    for (int i = s; i < e; ++i) {
        int c = scol[i];
        float wv = sval[i] * scl[c];
        acc = fmaf(wv, (float)Q[(size_t)c * 64 + lane], acc);
    }
    float m = acc;
#pragma unroll
    for (int o = 32; o >= 1; o >>= 1) m = fmaxf(m, __shfl_xor(m, o));
    float p = __expf(acc - m);
    float ssum = p;
#pragma unroll
    for (int o = 32; o >= 1; o >>= 1) ssum += __shfl_xor(ssum, o);
    out[(size_t)row * 64 + lane] = p / ssum;
}

// ---------------------------------------------------------------------------

extern "C" void kernel_launch(void* const* d_in, const int* in_sizes, int n_in,
                              void* d_out, int out_size, void* d_ws, size_t ws_size,
                              hipStream_t stream) {
    const float* X        = (const float*)d_in[0];
    const int*   edge_row = (const int*)d_in[1];
    const int*   edge_col = (const int*)d_in[2];
    const float* edge_val = (const float*)d_in[3];
    const float* W0       = (const float*)d_in[4];
    const float* Wh1      = (const float*)d_in[5];
    const float* W1       = (const float*)d_in[6];

    const int C = 512, H = 256, F = 64;
    const int N = in_sizes[0] / C;     // 100000
    const int E = in_sizes[1];         // 3200000

    size_t off = 0;
    auto alloc = [&](size_t bytes) -> void* {
        void* p = (char*)d_ws + off;
        off += (bytes + 255) & ~(size_t)255;
        return p;
    };
    // order matters: gemm_pre_k may overread A planes (Zhi/Zlo) by <=48KB,
    // so keep other live buffers after them.
    float* bufA   = (float*)alloc((size_t)N * H * sizeof(float));   // GEMM outs
    short* Zhi    = (short*)alloc((size_t)N * H * sizeof(short));   // SpMM out hi
    short* Zlo    = (short*)alloc((size_t)N * H * sizeof(short));   // SpMM out lo
    short* ZQ     = (short*)alloc((size_t)N * H * sizeof(short));   // quantized Z
    float* scl    = (float*)alloc((size_t)N * sizeof(float));
    int*   deg    = (int*)alloc((size_t)N * sizeof(int));
    int*   rowptr = (int*)alloc((size_t)(N + 1) * sizeof(int));
    int*   cursor = (int*)alloc((size_t)N * sizeof(int));
    int*   bsum   = (int*)alloc(128 * sizeof(int));
    int*   scol   = (int*)alloc((size_t)E * sizeof(int));
    float* sval   = (float*)alloc((size_t)E * sizeof(float));
    short* Bt0hi  = (short*)alloc((size_t)C * H * sizeof(short));
    short* Bt0lo  = (short*)alloc((size_t)C * H * sizeof(short));
    short* Bt1hi  = (short*)alloc((size_t)H * H * sizeof(short));
    short* Bt1lo  = (short*)alloc((size_t)H * H * sizeof(short));
    short* Bt2hi  = (short*)alloc((size_t)H * F * sizeof(short));
    short* Bt2lo  = (short*)alloc((size_t)H * F * sizeof(short));
    (void)ws_size;

    // ---- build CSR ----
    hipMemsetAsync(deg, 0, (size_t)N * sizeof(int), stream);
    count_rows_k<<<(E + 255) / 256, 256, 0, stream>>>(edge_row, deg, E);
    int nb = (N + SCAN_B - 1) / SCAN_B;
    scan1_k<<<nb, SCAN_B, 0, stream>>>(deg, rowptr, bsum, N);
    scan2_k<<<1, 128, 0, stream>>>(bsum, nb);
    scan3_k<<<nb, SCAN_B, 0, stream>>>(rowptr, bsum, cursor, N, E);
    scatter_k<<<(E + 255) / 256, 256, 0, stream>>>(edge_row, edge_col, edge_val,
                                                   cursor, scol, sval, E);

    // ---- prep weights ----
    split_w_k<<<(C * H + 255) / 256, 256, 0, stream>>>(W0, Bt0hi, Bt0lo, C, H);
    split_w_k<<<(H * H + 255) / 256, 256, 0, stream>>>(Wh1, Bt1hi, Bt1lo, H, H);
    split_w_k<<<(H * F + 255) / 256, 256, 0, stream>>>(W1, Bt2hi, Bt2lo, H, F);

    const int gx = (N + 127) / 128;              // 782
    const int rg = (N + 3) / 4;                  // row-parallel grids

    // ---- layer 0 ----
    gemm_split_k<512, 128><<<dim3(gx, 2), 256, 0, stream>>>(X, Bt0hi, Bt0lo, bufA, N, H);
    quant_rows_k<256><<<rg, 256, 0, stream>>>(bufA, ZQ, scl, N);
    spmm_agg256_k<<<rg, 256, 0, stream>>>(rowptr, scol, sval, ZQ, scl, Zhi, Zlo, N);
    // ---- layer 1 ----
    gemm_pre_k<256, 128><<<dim3(gx, 2), 256, 0, stream>>>(Zhi, Zlo, Bt1hi, Bt1lo, bufA, N, H);
    quant_rows_k<256><<<rg, 256, 0, stream>>>(bufA, ZQ, scl, N);
    spmm_agg256_k<<<rg, 256, 0, stream>>>(rowptr, scol, sval, ZQ, scl, Zhi, Zlo, N);
    // ---- layer 2 ----
    gemm_pre_k<256, 64><<<dim3(gx, 1), 256, 0, stream>>>(Zhi, Zlo, Bt2hi, Bt2lo, bufA, N, F);
    quant_rows_k<64><<<rg, 256, 0, stream>>>(bufA, ZQ, scl, N);
    spmm_softmax64_k<<<rg, 256, 0, stream>>>(rowptr, scol, sval, ZQ, scl,
                                             (float*)d_out, N);
}

// Round 4
// 1325.155 us; speedup vs baseline: 1.6184x; 1.2434x over previous
//
#include <hip/hip_runtime.h>
#include <cstdint>
#include <cstddef>

// ---------------------------------------------------------------------------
// GCN forward. CSR built on-device, rows padded to multiples of 4 edges so
// SpMM inner loops are tail-free with aligned int4/float4 index loads and
// 4 gathers in flight. GEMMs: bf16 3-term split-MFMA, wave = 32 rows x full
// output width, with per-row int16 quantization fused into the epilogue
// (writes ZQ int16 + per-row scale; no separate quant pass, no f32 buffer).
// SpMM gathers int16 rows, accumulates f32, writes bf16 hi/lo planes that
// feed the next GEMM directly.
// ---------------------------------------------------------------------------

#define SCAN_B 1024

typedef __attribute__((ext_vector_type(8))) short short8_t;
typedef __attribute__((ext_vector_type(4))) short short4_t;
typedef __attribute__((ext_vector_type(4))) float f32x4;

__device__ __forceinline__ short bf16_hi(float x) {
    union { float f; unsigned u; } c; c.f = x;
    return (short)(c.u >> 16);
}
__device__ __forceinline__ float bf16_f32(short h) {
    union { float f; unsigned u; } c; c.u = ((unsigned)(unsigned short)h) << 16;
    return c.f;
}

__device__ __forceinline__ void gload_lds16(const void* g, void* l) {
    __builtin_amdgcn_global_load_lds(
        (const __attribute__((address_space(1))) void*)g,
        (__attribute__((address_space(3))) void*)l, 16, 0, 0);
}

// ---------------- CSR construction (rows padded to %4) ----------------

__global__ void count_rows_k(const int* __restrict__ row, int* __restrict__ deg, int E) {
    int e = blockIdx.x * blockDim.x + threadIdx.x;
    if (e < E) atomicAdd(&deg[row[e]], 1);
}

__global__ __launch_bounds__(SCAN_B) void scan1_k(const int* __restrict__ deg,
                                                  int* __restrict__ part,
                                                  int* __restrict__ bsum, int n) {
    __shared__ int buf[SCAN_B];
    int tid = threadIdx.x;
    int i = blockIdx.x * SCAN_B + tid;
    int v = (i < n) ? ((deg[i] + 3) & ~3) : 0;     // padded degree
    buf[tid] = v;
    __syncthreads();
    for (int off = 1; off < SCAN_B; off <<= 1) {
        int y = (tid >= off) ? buf[tid - off] : 0;
        __syncthreads();
        buf[tid] += y;
        __syncthreads();
    }
    if (i < n) part[i] = buf[tid] - v;
    if (tid == SCAN_B - 1) bsum[blockIdx.x] = buf[tid];
}

__global__ __launch_bounds__(128) void scan2_k(int* __restrict__ bsum, int nb) {
    __shared__ int buf[128];
    int tid = threadIdx.x;
    int v = (tid < nb) ? bsum[tid] : 0;
    buf[tid] = v;
    __syncthreads();
    for (int off = 1; off < 128; off <<= 1) {
        int y = (tid >= off) ? buf[tid - off] : 0;
        __syncthreads();
        buf[tid] += y;
        __syncthreads();
    }
    if (tid < nb) bsum[tid] = buf[tid] - v;
    if (tid == nb - 1) bsum[nb] = buf[tid];        // grand total (padded E)
}

__global__ __launch_bounds__(SCAN_B) void scan3_k(int* __restrict__ rowptr,
                                                  const int* __restrict__ bsum,
                                                  int* __restrict__ cursor, int n, int nb) {
    int i = blockIdx.x * SCAN_B + threadIdx.x;
    if (i < n) {
        int v = rowptr[i] + bsum[blockIdx.x];
        rowptr[i] = v;
        cursor[i] = v;
    }
    if (i == 0) rowptr[n] = bsum[nb];
}

__global__ void scatter_k(const int* __restrict__ row, const int* __restrict__ col,
                          const float* __restrict__ val, int* __restrict__ cursor,
                          int* __restrict__ scol, float* __restrict__ sval, int E) {
    int e = blockIdx.x * blockDim.x + threadIdx.x;
    if (e < E) {
        int r = row[e];
        int p = atomicAdd(&cursor[r], 1);
        scol[p] = col[e];
        sval[p] = val[e];
    }
}

// ---------------- weight prep: split f32 W[K][M] -> bf16 Bt{hi,lo}[M][K] ----

__global__ void split_w_k(const float* __restrict__ W, short* __restrict__ Bthi,
                          short* __restrict__ Btlo, int K, int M) {
    int i = blockIdx.x * 256 + threadIdx.x;
    if (i >= K * M) return;
    int k = i / M, m = i - k * M;
    float x = W[i];
    short hi = bf16_hi(x);
    float r = x - bf16_f32(hi);
    short lo = bf16_hi(r);
    Bthi[(size_t)m * K + k] = hi;
    Btlo[(size_t)m * K + k] = lo;
}

// ---------------- fused quant epilogue (wave = 32 rows x BN cols) ----------
// C/D frag: col = n*16 + (lane&15), row = w*32 + m*16 + (lane>>4)*4 + r.
// Row max needs only a width-16 shfl reduce.

template <int NF>
__device__ __forceinline__ void quant_epilogue(f32x4 (&acc)[2][NF], int row0, int w,
                                               int lane, int N,
                                               short* __restrict__ ZQ,
                                               float* __restrict__ scl) {
    const int lg = lane >> 4;
    const int lc = lane & 15;
#pragma unroll
    for (int m = 0; m < 2; ++m) {
#pragma unroll
        for (int r = 0; r < 4; ++r) {
            float v = 0.f;
#pragma unroll
            for (int n = 0; n < NF; ++n) v = fmaxf(v, fabsf(acc[m][n][r]));
#pragma unroll
            for (int o = 8; o >= 1; o >>= 1) v = fmaxf(v, __shfl_xor(v, o));
            int grow = row0 + w * 32 + m * 16 + lg * 4 + r;
            if (grow < N) {
                float inv = (v > 0.f) ? 32767.f / v : 0.f;
                if (lc == 0) scl[grow] = v * (1.f / 32767.f);
#pragma unroll
                for (int n = 0; n < NF; ++n)
                    ZQ[(size_t)grow * (NF * 16) + n * 16 + lc] =
                        (short)rintf(acc[m][n][r] * inv);
            }
        }
    }
}

// ---------------- GEMM A (layer 0): f32 A, in-kernel split, fused quant ----
// 128 x BN tile (BN = full M), BK=32, 4 waves, wave owns 32 rows x BN cols.

template <int K, int BN>
__global__ __launch_bounds__(256) void gemm_fq_f32(const float* __restrict__ A,
                                                   const short* __restrict__ Bthi,
                                                   const short* __restrict__ Btlo,
                                                   short* __restrict__ ZQ,
                                                   float* __restrict__ scl, int N) {
    constexpr int NF = BN / 16;
    __shared__ short Ahi_s[128 * 32];
    __shared__ short Alo_s[128 * 32];
    __shared__ short Bhi_s[BN * 32];
    __shared__ short Blo_s[BN * 32];

    const int tid = threadIdx.x;
    const int lane = tid & 63;
    const int w = tid >> 6;
    const int row0 = blockIdx.x * 128;

    f32x4 acc[2][NF] = {};

    for (int k0 = 0; k0 < K; k0 += 32) {
#pragma unroll
        for (int h = 0; h < BN / 64; ++h) {
            int idx = h * 256 + tid;
            int cc = idx >> 2, q = idx & 3;
            size_t gb = (size_t)cc * K + k0 + q * 8;
            *(short8_t*)&Bhi_s[cc * 32 + q * 8] = *(const short8_t*)&Bthi[gb];
            *(short8_t*)&Blo_s[cc * 32 + q * 8] = *(const short8_t*)&Btlo[gb];
        }
#pragma unroll
        for (int h = 0; h < 4; ++h) {
            int idx = h * 256 + tid;
            int r = idx >> 3, q = idx & 7;
            int grow = row0 + r;
            float4 a = make_float4(0.f, 0.f, 0.f, 0.f);
            if (grow < N) a = *(const float4*)&A[(size_t)grow * K + k0 + q * 4];
            float ax[4] = {a.x, a.y, a.z, a.w};
            short4_t hi, lo;
#pragma unroll
            for (int j = 0; j < 4; ++j) {
                short h16 = bf16_hi(ax[j]);
                float rr = ax[j] - bf16_f32(h16);
                hi[j] = h16;
                lo[j] = bf16_hi(rr);
            }
            *(short4_t*)&Ahi_s[r * 32 + q * 4] = hi;
            *(short4_t*)&Alo_s[r * 32 + q * 4] = lo;
        }
        __syncthreads();

        const int kk = (lane >> 4) * 8;
        short8_t ah[2], al[2];
#pragma unroll
        for (int m = 0; m < 2; ++m) {
            int rr = w * 32 + m * 16 + (lane & 15);
            ah[m] = *(const short8_t*)&Ahi_s[rr * 32 + kk];
            al[m] = *(const short8_t*)&Alo_s[rr * 32 + kk];
        }
#pragma unroll
        for (int n = 0; n < NF; ++n) {
            int cc = n * 16 + (lane & 15);
            short8_t bh = *(const short8_t*)&Bhi_s[cc * 32 + kk];
            short8_t bl = *(const short8_t*)&Blo_s[cc * 32 + kk];
#pragma unroll
            for (int m = 0; m < 2; ++m) {
                acc[m][n] = __builtin_amdgcn_mfma_f32_16x16x32_bf16(ah[m], bh, acc[m][n], 0, 0, 0);
                acc[m][n] = __builtin_amdgcn_mfma_f32_16x16x32_bf16(ah[m], bl, acc[m][n], 0, 0, 0);
                acc[m][n] = __builtin_amdgcn_mfma_f32_16x16x32_bf16(al[m], bh, acc[m][n], 0, 0, 0);
            }
        }
        __syncthreads();
    }

    quant_epilogue<NF>(acc, row0, w, lane, N, ZQ, scl);
}

// ---------------- GEMM B (layers 1-2): pre-split bf16 A planes -------------
// Staging via global_load_lds width=16, linear LDS. May overread A planes by
// up to 96 rows past N — keep allocated buffers after them.

template <int K, int BN>
__global__ __launch_bounds__(256) void gemm_fq_pre(const short* __restrict__ Ahi,
                                                   const short* __restrict__ Alo,
                                                   const short* __restrict__ Bthi,
                                                   const short* __restrict__ Btlo,
                                                   short* __restrict__ ZQ,
                                                   float* __restrict__ scl, int N) {
    constexpr int NF = BN / 16;
    __shared__ short Ahi_s[128 * 32];
    __shared__ short Alo_s[128 * 32];
    __shared__ short Bhi_s[BN * 32];
    __shared__ short Blo_s[BN * 32];

    const int tid = threadIdx.x;
    const int lane = tid & 63;
    const int w = tid >> 6;
    const int row0 = blockIdx.x * 128;

    f32x4 acc[2][NF] = {};

    const int crow = lane >> 2;          // 0..15
    const int ckq  = (lane & 3) * 8;     // 0,8,16,24 (bf16)

    for (int k0 = 0; k0 < K; k0 += 32) {
        for (int ch = w; ch < 8; ch += 4) {
            size_t ga = (size_t)(row0 + ch * 16 + crow) * K + k0 + ckq;
            gload_lds16(&Ahi[ga], &Ahi_s[ch * 512]);
            gload_lds16(&Alo[ga], &Alo_s[ch * 512]);
        }
        for (int ch = w; ch < BN / 16; ch += 4) {
            size_t gb = (size_t)(ch * 16 + crow) * K + k0 + ckq;
            gload_lds16(&Bthi[gb], &Bhi_s[ch * 512]);
            gload_lds16(&Btlo[gb], &Blo_s[ch * 512]);
        }
        __syncthreads();

        const int kk = (lane >> 4) * 8;
        short8_t ah[2], al[2];
#pragma unroll
        for (int m = 0; m < 2; ++m) {
            int rr = w * 32 + m * 16 + (lane & 15);
            ah[m] = *(const short8_t*)&Ahi_s[rr * 32 + kk];
            al[m] = *(const short8_t*)&Alo_s[rr * 32 + kk];
        }
#pragma unroll
        for (int n = 0; n < NF; ++n) {
            int cc = n * 16 + (lane & 15);
            short8_t bh = *(const short8_t*)&Bhi_s[cc * 32 + kk];
            short8_t bl = *(const short8_t*)&Blo_s[cc * 32 + kk];
#pragma unroll
            for (int m = 0; m < 2; ++m) {
                acc[m][n] = __builtin_amdgcn_mfma_f32_16x16x32_bf16(ah[m], bh, acc[m][n], 0, 0, 0);
                acc[m][n] = __builtin_amdgcn_mfma_f32_16x16x32_bf16(ah[m], bl, acc[m][n], 0, 0, 0);
                acc[m][n] = __builtin_amdgcn_mfma_f32_16x16x32_bf16(al[m], bh, acc[m][n], 0, 0, 0);
            }
        }
        __syncthreads();
    }

    quant_epilogue<NF>(acc, row0, w, lane, N, ZQ, scl);
}

// ---------------- SpMM (CSR, padded rows), one wave per dest row -----------

// d=256: 4 gathers of short4 (512B/wave each) in flight; relu + bf16 split out.
__global__ __launch_bounds__(256) void spmm_agg256_k(const int* __restrict__ rowptr,
                                                     const int* __restrict__ scol,
                                                     const float* __restrict__ sval,
                                                     const short* __restrict__ Q,
                                                     const float* __restrict__ scl,
                                                     short* __restrict__ Zhi,
                                                     short* __restrict__ Zlo, int N) {
    int row = blockIdx.x * 4 + (threadIdx.x >> 6);
    if (row >= N) return;
    int lane = threadIdx.x & 63;
    int s = rowptr[row], e = rowptr[row + 1];   // both %4
    const short4_t* Qv = (const short4_t*)Q;
    f32x4 acc = {0.f, 0.f, 0.f, 0.f};
    for (int i = s; i < e; i += 4) {
        int4 c4 = *(const int4*)&scol[i];
        float4 v4 = *(const float4*)&sval[i];
        float w0 = v4.x * scl[c4.x];
        float w1 = v4.y * scl[c4.y];
        float w2 = v4.z * scl[c4.z];
        float w3 = v4.w * scl[c4.w];
        short4_t q0 = Qv[(size_t)c4.x * 64 + lane];
        short4_t q1 = Qv[(size_t)c4.y * 64 + lane];
        short4_t q2 = Qv[(size_t)c4.z * 64 + lane];
        short4_t q3 = Qv[(size_t)c4.w * 64 + lane];
#pragma unroll
        for (int j = 0; j < 4; ++j) {
            acc[j] = fmaf(w0, (float)q0[j], acc[j]);
            acc[j] = fmaf(w1, (float)q1[j], acc[j]);
            acc[j] = fmaf(w2, (float)q2[j], acc[j]);
            acc[j] = fmaf(w3, (float)q3[j], acc[j]);
        }
    }
    short4_t hi, lo;
#pragma unroll
    for (int j = 0; j < 4; ++j) {
        float r = fmaxf(acc[j], 0.f);
        short h = bf16_hi(r);
        hi[j] = h;
        lo[j] = bf16_hi(r - bf16_f32(h));
    }
    ((short4_t*)Zhi)[(size_t)row * 64 + lane] = hi;
    ((short4_t*)Zlo)[(size_t)row * 64 + lane] = lo;
}

// d=64: 4 gathers of short (128B/wave each) in flight; fused row softmax.
__global__ __launch_bounds__(256) void spmm_softmax64_k(const int* __restrict__ rowptr,
                                                        const int* __restrict__ scol,
                                                        const float* __restrict__ sval,
                                                        const short* __restrict__ Q,
                                                        const float* __restrict__ scl,
                                                        float* __restrict__ out, int N) {
    int row = blockIdx.x * 4 + (threadIdx.x >> 6);
    if (row >= N) return;
    int lane = threadIdx.x & 63;
    int s = rowptr[row], e = rowptr[row + 1];
    float acc = 0.f;
    for (int i = s; i < e; i += 4) {
        int4 c4 = *(const int4*)&scol[i];
        float4 v4 = *(const float4*)&sval[i];
        float w0 = v4.x * scl[c4.x];
        float w1 = v4.y * scl[c4.y];
        float w2 = v4.z * scl[c4.z];
        float w3 = v4.w * scl[c4.w];
        float z0 = (float)Q[(size_t)c4.x * 64 + lane];
        float z1 = (float)Q[(size_t)c4.y * 64 + lane];
        float z2 = (float)Q[(size_t)c4.z * 64 + lane];
        float z3 = (float)Q[(size_t)c4.w * 64 + lane];
        acc = fmaf(w0, z0, acc);
        acc = fmaf(w1, z1, acc);
        acc = fmaf(w2, z2, acc);
        acc = fmaf(w3, z3, acc);
    }
    float m = acc;
#pragma unroll
    for (int o = 32; o >= 1; o >>= 1) m = fmaxf(m, __shfl_xor(m, o));
    float p = __expf(acc - m);
    float ssum = p;
#pragma unroll
    for (int o = 32; o >= 1; o >>= 1) ssum += __shfl_xor(ssum, o);
    out[(size_t)row * 64 + lane] = p / ssum;
}

// ---------------------------------------------------------------------------

extern "C" void kernel_launch(void* const* d_in, const int* in_sizes, int n_in,
                              void* d_out, int out_size, void* d_ws, size_t ws_size,
                              hipStream_t stream) {
    const float* X        = (const float*)d_in[0];
    const int*   edge_row = (const int*)d_in[1];
    const int*   edge_col = (const int*)d_in[2];
    const float* edge_val = (const float*)d_in[3];
    const float* W0       = (const float*)d_in[4];
    const float* Wh1      = (const float*)d_in[5];
    const float* W1       = (const float*)d_in[6];

    const int C = 512, H = 256, F = 64;
    const int N = in_sizes[0] / C;     // 100000
    const int E = in_sizes[1];         // 3200000
    const int EPAD = E + 4 * N + 64;   // padded-edge capacity

    size_t off = 0;
    auto alloc = [&](size_t bytes) -> void* {
        void* p = (char*)d_ws + off;
        off += (bytes + 255) & ~(size_t)255;
        return p;
    };
    // order matters: gemm_fq_pre overreads Zhi/Zlo by <=48KB each.
    short* Zhi    = (short*)alloc((size_t)N * H * sizeof(short));
    short* Zlo    = (short*)alloc((size_t)N * H * sizeof(short));
    short* ZQ     = (short*)alloc((size_t)N * H * sizeof(short));
    float* scl    = (float*)alloc((size_t)N * sizeof(float));
    int*   deg    = (int*)alloc((size_t)N * sizeof(int));
    int*   rowptr = (int*)alloc((size_t)(N + 1) * sizeof(int));
    int*   cursor = (int*)alloc((size_t)N * sizeof(int));
    int*   bsum   = (int*)alloc(129 * sizeof(int));
    int*   scol   = (int*)alloc((size_t)EPAD * sizeof(int));
    float* sval   = (float*)alloc((size_t)EPAD * sizeof(float));
    short* Bt0hi  = (short*)alloc((size_t)C * H * sizeof(short));
    short* Bt0lo  = (short*)alloc((size_t)C * H * sizeof(short));
    short* Bt1hi  = (short*)alloc((size_t)H * H * sizeof(short));
    short* Bt1lo  = (short*)alloc((size_t)H * H * sizeof(short));
    short* Bt2hi  = (short*)alloc((size_t)H * F * sizeof(short));
    short* Bt2lo  = (short*)alloc((size_t)H * F * sizeof(short));
    (void)ws_size;

    // ---- build padded CSR ----
    hipMemsetAsync(deg, 0, (size_t)N * sizeof(int), stream);
    hipMemsetAsync(scol, 0, (size_t)EPAD * sizeof(int), stream);
    hipMemsetAsync(sval, 0, (size_t)EPAD * sizeof(float), stream);
    count_rows_k<<<(E + 255) / 256, 256, 0, stream>>>(edge_row, deg, E);
    int nb = (N + SCAN_B - 1) / SCAN_B;          // 98 <= 128
    scan1_k<<<nb, SCAN_B, 0, stream>>>(deg, rowptr, bsum, N);
    scan2_k<<<1, 128, 0, stream>>>(bsum, nb);
    scan3_k<<<nb, SCAN_B, 0, stream>>>(rowptr, bsum, cursor, N, nb);
    scatter_k<<<(E + 255) / 256, 256, 0, stream>>>(edge_row, edge_col, edge_val,
                                                   cursor, scol, sval, E);

    // ---- prep weights ----
    split_w_k<<<(C * H + 255) / 256, 256, 0, stream>>>(W0, Bt0hi, Bt0lo, C, H);
    split_w_k<<<(H * H + 255) / 256, 256, 0, stream>>>(Wh1, Bt1hi, Bt1lo, H, H);
    split_w_k<<<(H * F + 255) / 256, 256, 0, stream>>>(W1, Bt2hi, Bt2lo, H, F);

    const int gx = (N + 127) / 128;              // 782
    const int rg = (N + 3) / 4;                  // 25000

    // ---- layer 0 ----
    gemm_fq_f32<512, 256><<<gx, 256, 0, stream>>>(X, Bt0hi, Bt0lo, ZQ, scl, N);
    spmm_agg256_k<<<rg, 256, 0, stream>>>(rowptr, scol, sval, ZQ, scl, Zhi, Zlo, N);
    // ---- layer 1 ----
    gemm_fq_pre<256, 256><<<gx, 256, 0, stream>>>(Zhi, Zlo, Bt1hi, Bt1lo, ZQ, scl, N);
    spmm_agg256_k<<<rg, 256, 0, stream>>>(rowptr, scol, sval, ZQ, scl, Zhi, Zlo, N);
    // ---- layer 2 ----
    gemm_fq_pre<256, 64><<<gx, 256, 0, stream>>>(Zhi, Zlo, Bt2hi, Bt2lo, ZQ, scl, N);
    spmm_softmax64_k<<<rg, 256, 0, stream>>>(rowptr, scol, sval, ZQ, scl,
                                             (float*)d_out, N);
}

// Round 5
// 1160.753 us; speedup vs baseline: 1.8476x; 1.1416x over previous
//
#include <hip/hip_runtime.h>
#include <cstdint>
#include <cstddef>

// ---------------------------------------------------------------------------
// GCN forward. CSR built on-device (rows padded %4). SpMM gathers per-row
// int16-quantized Z, accumulates f32, relu, writes f32 Z. GEMMs: one template
// for all layers: A = f32 (global_load_lds staged, converted to bf16 hi/lo at
// fragment read), B = pre-split interleaved bf16 hi/lo, 3-term split-MFMA,
// XOR-8 swizzled LDS (linear dest + pre-swizzled source), fused per-row
// int16 quantization epilogue.
// ---------------------------------------------------------------------------

#define SCAN_B 1024

typedef __attribute__((ext_vector_type(8))) short short8_t;
typedef __attribute__((ext_vector_type(4))) short short4_t;
typedef __attribute__((ext_vector_type(4))) float f32x4;

__device__ __forceinline__ short bf16_hi(float x) {
    union { float f; unsigned u; } c; c.f = x;
    return (short)(c.u >> 16);
}
__device__ __forceinline__ float bf16_f32(short h) {
    union { float f; unsigned u; } c; c.u = ((unsigned)(unsigned short)h) << 16;
    return c.f;
}

__device__ __forceinline__ void gload_lds16(const void* g, void* l) {
    __builtin_amdgcn_global_load_lds(
        (const __attribute__((address_space(1))) void*)g,
        (__attribute__((address_space(3))) void*)l, 16, 0, 0);
}

// ---------------- CSR construction (rows padded to %4) ----------------

__global__ void count_rows_k(const int* __restrict__ row, int* __restrict__ deg, int E) {
    int e = blockIdx.x * blockDim.x + threadIdx.x;
    if (e < E) atomicAdd(&deg[row[e]], 1);
}

__global__ __launch_bounds__(SCAN_B) void scan1_k(const int* __restrict__ deg,
                                                  int* __restrict__ part,
                                                  int* __restrict__ bsum, int n) {
    __shared__ int buf[SCAN_B];
    int tid = threadIdx.x;
    int i = blockIdx.x * SCAN_B + tid;
    int v = (i < n) ? ((deg[i] + 3) & ~3) : 0;     // padded degree
    buf[tid] = v;
    __syncthreads();
    for (int off = 1; off < SCAN_B; off <<= 1) {
        int y = (tid >= off) ? buf[tid - off] : 0;
        __syncthreads();
        buf[tid] += y;
        __syncthreads();
    }
    if (i < n) part[i] = buf[tid] - v;
    if (tid == SCAN_B - 1) bsum[blockIdx.x] = buf[tid];
}

__global__ __launch_bounds__(128) void scan2_k(int* __restrict__ bsum, int nb) {
    __shared__ int buf[128];
    int tid = threadIdx.x;
    int v = (tid < nb) ? bsum[tid] : 0;
    buf[tid] = v;
    __syncthreads();
    for (int off = 1; off < 128; off <<= 1) {
        int y = (tid >= off) ? buf[tid - off] : 0;
        __syncthreads();
        buf[tid] += y;
        __syncthreads();
    }
    if (tid < nb) bsum[tid] = buf[tid] - v;
    if (tid == nb - 1) bsum[nb] = buf[tid];        // grand total (padded E)
}

__global__ __launch_bounds__(SCAN_B) void scan3_k(int* __restrict__ rowptr,
                                                  const int* __restrict__ bsum,
                                                  int* __restrict__ cursor, int n, int nb) {
    int i = blockIdx.x * SCAN_B + threadIdx.x;
    if (i < n) {
        int v = rowptr[i] + bsum[blockIdx.x];
        rowptr[i] = v;
        cursor[i] = v;
    }
    if (i == 0) rowptr[n] = bsum[nb];
}

__global__ void scatter_k(const int* __restrict__ row, const int* __restrict__ col,
                          const float* __restrict__ val, int* __restrict__ cursor,
                          int* __restrict__ scol, float* __restrict__ sval, int E) {
    int e = blockIdx.x * blockDim.x + threadIdx.x;
    if (e < E) {
        int r = row[e];
        int p = atomicAdd(&cursor[r], 1);
        scol[p] = col[e];
        sval[p] = val[e];
    }
}

// ------- weight prep: W[K][M] f32 -> Bhl[M][2K] bf16, interleaved ----------
// Per col m, K split into groups of 8: [hi(8) | lo(8)] per group.

__global__ void split_w_k(const float* __restrict__ W, short* __restrict__ Bhl,
                          int K, int M) {
    int i = blockIdx.x * 256 + threadIdx.x;
    if (i >= K * M) return;
    int k = i / M, m = i - k * M;
    float x = W[i];
    short hi = bf16_hi(x);
    float r = x - bf16_f32(hi);
    short lo = bf16_hi(r);
    int g = k >> 3, j = k & 7;
    Bhl[(size_t)m * (2 * K) + 16 * g + j] = hi;
    Bhl[(size_t)m * (2 * K) + 16 * g + 8 + j] = lo;
}

// ---------------- unified split-MFMA GEMM with fused int16 quant -----------
// C[N,BN] = A[N,K] (f32) * B[K,BN]; 4 waves as (4/NWC) x NWC grid,
// wave = 32 rows x (BN/NWC) cols. LDS rows are 128B with XOR-8 slot swizzle:
// phys_slot = logical_slot ^ (row&7); staged linearly by global_load_lds with
// the XOR applied to the per-lane GLOBAL source address.
// A fragment (f32) converted to bf16 hi/lo in-register at read time.
// Epilogue: per-row absmax (shfl + tiny LDS across wc), int16 quant -> ZQ,scl.

template <int K, int BN, int NWC>
__global__ __launch_bounds__(256) void gemm_fq(const float* __restrict__ A,
                                               const short* __restrict__ Bhl,
                                               short* __restrict__ ZQ,
                                               float* __restrict__ scl, int N) {
    constexpr int NWR = 4 / NWC;
    constexpr int BM  = 32 * NWR;
    constexpr int NF  = BN / NWC / 16;
    __shared__ float Ald[BM * 32];     // [row][32 f32] = 128B rows, swizzled
    __shared__ short Bld[BN * 64];     // [col][64 sh]  = 128B rows, swizzled

    const int tid = threadIdx.x, lane = tid & 63, w = tid >> 6;
    const int wr = w / NWC, wc = w % NWC;
    const int row0 = blockIdx.x * BM;
    const int l8 = lane >> 3;                       // 0..7 (row within chunk)
    const int slotx = (lane & 7) ^ (l8 & 7);        // pre-swizzled source slot
    const bool full = (row0 + BM <= N);

    f32x4 acc[2][NF] = {};

    for (int k0 = 0; k0 < K; k0 += 32) {
        // ---- stage A (f32, 8-row chunks of 1KB) ----
        if (full) {
            for (int ch = w; ch < BM / 8; ch += 4)
                gload_lds16(A + (size_t)(row0 + ch * 8 + l8) * K + k0 + slotx * 4,
                            &Ald[ch * 256]);
        } else {
            for (int ch = w; ch < BM / 8; ch += 4) {
                int r_ = row0 + ch * 8 + l8;
                float4 v = make_float4(0.f, 0.f, 0.f, 0.f);
                if (r_ < N) v = *(const float4*)(A + (size_t)r_ * K + k0 + slotx * 4);
                *(float4*)((char*)&Ald[ch * 256] + lane * 16) = v;
            }
        }
        // ---- stage B (interleaved hi/lo, 8-col chunks of 1KB) ----
        for (int ch = w; ch < BN / 8; ch += 4)
            gload_lds16(Bhl + (size_t)(ch * 8 + l8) * (2 * K) + 2 * k0 + slotx * 8,
                        &Bld[ch * 512]);
        __syncthreads();

        const int g2 = (lane >> 4) * 2;             // logical slot base (k-half)
        short8_t ah[2], al[2];
#pragma unroll
        for (int m = 0; m < 2; ++m) {
            int rl = wr * 32 + m * 16 + (lane & 15);
            int key = rl & 7;
            f32x4 a0 = *(const f32x4*)&Ald[rl * 32 + ((g2 ^ key) * 4)];
            f32x4 a1 = *(const f32x4*)&Ald[rl * 32 + (((g2 + 1) ^ key) * 4)];
            float f[8] = {a0[0], a0[1], a0[2], a0[3], a1[0], a1[1], a1[2], a1[3]};
#pragma unroll
            for (int j = 0; j < 8; ++j) {
                short hh = bf16_hi(f[j]);
                ah[m][j] = hh;
                al[m][j] = bf16_hi(f[j] - bf16_f32(hh));
            }
        }
#pragma unroll
        for (int n = 0; n < NF; ++n) {
            int cl = wc * (BN / NWC) + n * 16 + (lane & 15);
            int key = cl & 7;
            short8_t bh = *(const short8_t*)&Bld[cl * 64 + ((g2 ^ key) * 8)];
            short8_t bl = *(const short8_t*)&Bld[cl * 64 + (((g2 + 1) ^ key) * 8)];
#pragma unroll
            for (int m = 0; m < 2; ++m) {
                acc[m][n] = __builtin_amdgcn_mfma_f32_16x16x32_bf16(ah[m], bh, acc[m][n], 0, 0, 0);
                acc[m][n] = __builtin_amdgcn_mfma_f32_16x16x32_bf16(ah[m], bl, acc[m][n], 0, 0, 0);
                acc[m][n] = __builtin_amdgcn_mfma_f32_16x16x32_bf16(al[m], bh, acc[m][n], 0, 0, 0);
            }
        }
        __syncthreads();
    }

    // ---- fused quant epilogue ----
    const int lg = lane >> 4, lc = lane & 15;
    float* maxb = Ald;                 // reuse A-LDS (all reads done, post-barrier)
    float rmax[2][4];
#pragma unroll
    for (int m = 0; m < 2; ++m)
#pragma unroll
        for (int r = 0; r < 4; ++r) {
            float v = 0.f;
#pragma unroll
            for (int n = 0; n < NF; ++n) v = fmaxf(v, fabsf(acc[m][n][r]));
#pragma unroll
            for (int o = 8; o >= 1; o >>= 1) v = fmaxf(v, __shfl_xor(v, o));
            rmax[m][r] = v;
        }
    if constexpr (NWC > 1) {
        if (lc == 0)
#pragma unroll
            for (int m = 0; m < 2; ++m)
#pragma unroll
                for (int r = 0; r < 4; ++r)
                    maxb[(wr * 32 + m * 16 + lg * 4 + r) * NWC + wc] = rmax[m][r];
        __syncthreads();
    }
#pragma unroll
    for (int m = 0; m < 2; ++m)
#pragma unroll
        for (int r = 0; r < 4; ++r) {
            int rl = wr * 32 + m * 16 + lg * 4 + r;
            float v = rmax[m][r];
            if constexpr (NWC > 1) {
                v = maxb[rl * NWC];
#pragma unroll
                for (int q = 1; q < NWC; ++q) v = fmaxf(v, maxb[rl * NWC + q]);
            }
            int grow = row0 + rl;
            if (grow < N) {
                float inv = (v > 0.f) ? 32767.f / v : 0.f;
                if (lc == 0 && wc == 0) scl[grow] = v * (1.f / 32767.f);
#pragma unroll
                for (int n = 0; n < NF; ++n)
                    ZQ[(size_t)grow * BN + wc * (BN / NWC) + n * 16 + lc] =
                        (short)rintf(acc[m][n][r] * inv);
            }
        }
}

// ---------------- SpMM (CSR, padded rows), one wave per dest row -----------

// d=256: 4 gathers of short4 in flight; relu; f32 out.
__global__ __launch_bounds__(256) void spmm_agg256_k(const int* __restrict__ rowptr,
                                                     const int* __restrict__ scol,
                                                     const float* __restrict__ sval,
                                                     const short* __restrict__ Q,
                                                     const float* __restrict__ scl,
                                                     float* __restrict__ Z, int N) {
    int row = blockIdx.x * 4 + (threadIdx.x >> 6);
    if (row >= N) return;
    int lane = threadIdx.x & 63;
    int s = rowptr[row], e = rowptr[row + 1];   // both %4
    const short4_t* Qv = (const short4_t*)Q;
    f32x4 acc = {0.f, 0.f, 0.f, 0.f};
    for (int i = s; i < e; i += 4) {
        int4 c4 = *(const int4*)&scol[i];
        float4 v4 = *(const float4*)&sval[i];
        float w0 = v4.x * scl[c4.x];
        float w1 = v4.y * scl[c4.y];
        float w2 = v4.z * scl[c4.z];
        float w3 = v4.w * scl[c4.w];
        short4_t q0 = Qv[(size_t)c4.x * 64 + lane];
        short4_t q1 = Qv[(size_t)c4.y * 64 + lane];
        short4_t q2 = Qv[(size_t)c4.z * 64 + lane];
        short4_t q3 = Qv[(size_t)c4.w * 64 + lane];
#pragma unroll
        for (int j = 0; j < 4; ++j) {
            acc[j] = fmaf(w0, (float)q0[j], acc[j]);
            acc[j] = fmaf(w1, (float)q1[j], acc[j]);
            acc[j] = fmaf(w2, (float)q2[j], acc[j]);
            acc[j] = fmaf(w3, (float)q3[j], acc[j]);
        }
    }
    float4 out = make_float4(fmaxf(acc[0], 0.f), fmaxf(acc[1], 0.f),
                             fmaxf(acc[2], 0.f), fmaxf(acc[3], 0.f));
    ((float4*)Z)[(size_t)row * 64 + lane] = out;
}

// d=64: 4 gathers of short in flight; fused row softmax.
__global__ __launch_bounds__(256) void spmm_softmax64_k(const int* __restrict__ rowptr,
                                                        const int* __restrict__ scol,
                                                        const float* __restrict__ sval,
                                                        const short* __restrict__ Q,
                                                        const float* __restrict__ scl,
                                                        float* __restrict__ out, int N) {
    int row = blockIdx.x * 4 + (threadIdx.x >> 6);
    if (row >= N) return;
    int lane = threadIdx.x & 63;
    int s = rowptr[row], e = rowptr[row + 1];
    float acc = 0.f;
    for (int i = s; i < e; i += 4) {
        int4 c4 = *(const int4*)&scol[i];
        float4 v4 = *(const float4*)&sval[i];
        float w0 = v4.x * scl[c4.x];
        float w1 = v4.y * scl[c4.y];
        float w2 = v4.z * scl[c4.z];
        float w3 = v4.w * scl[c4.w];
        float z0 = (float)Q[(size_t)c4.x * 64 + lane];
        float z1 = (float)Q[(size_t)c4.y * 64 + lane];
        float z2 = (float)Q[(size_t)c4.z * 64 + lane];
        float z3 = (float)Q[(size_t)c4.w * 64 + lane];
        acc = fmaf(w0, z0, acc);
        acc = fmaf(w1, z1, acc);
        acc = fmaf(w2, z2, acc);
        acc = fmaf(w3, z3, acc);
    }
    float m = acc;
#pragma unroll
    for (int o = 32; o >= 1; o >>= 1) m = fmaxf(m, __shfl_xor(m, o));
    float p = __expf(acc - m);
    float ssum = p;
#pragma unroll
    for (int o = 32; o >= 1; o >>= 1) ssum += __shfl_xor(ssum, o);
    out[(size_t)row * 64 + lane] = p / ssum;
}

// ---------------------------------------------------------------------------

extern "C" void kernel_launch(void* const* d_in, const int* in_sizes, int n_in,
                              void* d_out, int out_size, void* d_ws, size_t ws_size,
                              hipStream_t stream) {
    const float* X        = (const float*)d_in[0];
    const int*   edge_row = (const int*)d_in[1];
    const int*   edge_col = (const int*)d_in[2];
    const float* edge_val = (const float*)d_in[3];
    const float* W0       = (const float*)d_in[4];
    const float* Wh1      = (const float*)d_in[5];
    const float* W1       = (const float*)d_in[6];

    const int C = 512, H = 256, F = 64;
    const int N = in_sizes[0] / C;     // 100000
    const int E = in_sizes[1];         // 3200000
    const int EPAD = E + 4 * N + 64;   // padded-edge capacity

    size_t off = 0;
    auto alloc = [&](size_t bytes) -> void* {
        void* p = (char*)d_ws + off;
        off += (bytes + 255) & ~(size_t)255;
        return p;
    };
    // Z first: gemm_fq overreads A (=Z) by <=96KB; ZQ etc. follow as slack.
    float* Z      = (float*)alloc((size_t)N * H * sizeof(float));
    short* ZQ     = (short*)alloc((size_t)N * H * sizeof(short));
    float* scl    = (float*)alloc((size_t)N * sizeof(float));
    int*   deg    = (int*)alloc((size_t)N * sizeof(int));
    int*   rowptr = (int*)alloc((size_t)(N + 1) * sizeof(int));
    int*   cursor = (int*)alloc((size_t)N * sizeof(int));
    int*   bsum   = (int*)alloc(129 * sizeof(int));
    int*   scol   = (int*)alloc((size_t)EPAD * sizeof(int));
    float* sval   = (float*)alloc((size_t)EPAD * sizeof(float));
    short* Bhl0   = (short*)alloc((size_t)H * 2 * C * sizeof(short));   // [256][1024]
    short* Bhl1   = (short*)alloc((size_t)H * 2 * H * sizeof(short));   // [256][512]
    short* Bhl2   = (short*)alloc((size_t)F * 2 * H * sizeof(short));   // [64][512]
    (void)ws_size;

    // ---- build padded CSR ----
    hipMemsetAsync(deg, 0, (size_t)N * sizeof(int), stream);
    hipMemsetAsync(scol, 0, (size_t)EPAD * sizeof(int), stream);
    hipMemsetAsync(sval, 0, (size_t)EPAD * sizeof(float), stream);
    count_rows_k<<<(E + 255) / 256, 256, 0, stream>>>(edge_row, deg, E);
    int nb = (N + SCAN_B - 1) / SCAN_B;          // 98 <= 128
    scan1_k<<<nb, SCAN_B, 0, stream>>>(deg, rowptr, bsum, N);
    scan2_k<<<1, 128, 0, stream>>>(bsum, nb);
    scan3_k<<<nb, SCAN_B, 0, stream>>>(rowptr, bsum, cursor, N, nb);
    scatter_k<<<(E + 255) / 256, 256, 0, stream>>>(edge_row, edge_col, edge_val,
                                                   cursor, scol, sval, E);

    // ---- prep weights (split + transpose + interleave) ----
    split_w_k<<<(C * H + 255) / 256, 256, 0, stream>>>(W0, Bhl0, C, H);
    split_w_k<<<(H * H + 255) / 256, 256, 0, stream>>>(Wh1, Bhl1, H, H);
    split_w_k<<<(H * F + 255) / 256, 256, 0, stream>>>(W1, Bhl2, H, F);

    const int g64  = (N + 63) / 64;              // 1563
    const int g128 = (N + 127) / 128;            // 782
    const int rg   = (N + 3) / 4;                // 25000

    // ---- layer 0 ----
    gemm_fq<512, 256, 2><<<g64, 256, 0, stream>>>(X, Bhl0, ZQ, scl, N);
    spmm_agg256_k<<<rg, 256, 0, stream>>>(rowptr, scol, sval, ZQ, scl, Z, N);
    // ---- layer 1 ----
    gemm_fq<256, 256, 2><<<g64, 256, 0, stream>>>(Z, Bhl1, ZQ, scl, N);
    spmm_agg256_k<<<rg, 256, 0, stream>>>(rowptr, scol, sval, ZQ, scl, Z, N);
    // ---- layer 2 ----
    gemm_fq<256, 64, 1><<<g128, 256, 0, stream>>>(Z, Bhl2, ZQ, scl, N);
    spmm_softmax64_k<<<rg, 256, 0, stream>>>(rowptr, scol, sval, ZQ, scl,
                                             (float*)d_out, N);
}

// Round 6
// 1135.529 us; speedup vs baseline: 1.8887x; 1.0222x over previous
//
#include <hip/hip_runtime.h>
#include <cstdint>
#include <cstddef>

// ---------------------------------------------------------------------------
// GCN forward. CSR built on-device (rows padded %4, packed (col,val) pairs).
// SpMM gathers per-row int16-quantized rows, accumulates f32, writes
// interleaved bf16 hi/lo planes (Zhl) that are the next GEMM's A operand.
// GEMM: unified 3-term split-MFMA, wave = 64 rows x 64 cols (MFMA-bound),
// A & B both interleaved hi8|lo8 bf16 in LDS with XOR-8 slot swizzle
// (linear LDS dest + pre-swizzled global source for gload; swizzled ds_write
// for the L0 f32 path). Fused per-row int16 quantization epilogue.
// ---------------------------------------------------------------------------

#define SCAN_B 1024

typedef __attribute__((ext_vector_type(8))) short short8_t;
typedef __attribute__((ext_vector_type(4))) short short4_t;
typedef __attribute__((ext_vector_type(4))) float f32x4;

__device__ __forceinline__ short bf16_hi(float x) {
    union { float f; unsigned u; } c; c.f = x;
    return (short)(c.u >> 16);
}
__device__ __forceinline__ float bf16_f32(short h) {
    union { float f; unsigned u; } c; c.u = ((unsigned)(unsigned short)h) << 16;
    return c.f;
}

__device__ __forceinline__ void gload_lds16(const void* g, void* l) {
    __builtin_amdgcn_global_load_lds(
        (const __attribute__((address_space(1))) void*)g,
        (__attribute__((address_space(3))) void*)l, 16, 0, 0);
}

// ---------------- CSR construction (rows padded to %4) ----------------

__global__ void count_rows_k(const int* __restrict__ row, int* __restrict__ deg, int E) {
    int e = blockIdx.x * blockDim.x + threadIdx.x;
    if (e < E) atomicAdd(&deg[row[e]], 1);
}

__global__ __launch_bounds__(SCAN_B) void scan1_k(const int* __restrict__ deg,
                                                  int* __restrict__ part,
                                                  int* __restrict__ bsum, int n) {
    __shared__ int buf[SCAN_B];
    int tid = threadIdx.x;
    int i = blockIdx.x * SCAN_B + tid;
    int v = (i < n) ? ((deg[i] + 3) & ~3) : 0;     // padded degree
    buf[tid] = v;
    __syncthreads();
    for (int off = 1; off < SCAN_B; off <<= 1) {
        int y = (tid >= off) ? buf[tid - off] : 0;
        __syncthreads();
        buf[tid] += y;
        __syncthreads();
    }
    if (i < n) part[i] = buf[tid] - v;
    if (tid == SCAN_B - 1) bsum[blockIdx.x] = buf[tid];
}

__global__ __launch_bounds__(128) void scan2_k(int* __restrict__ bsum, int nb) {
    __shared__ int buf[128];
    int tid = threadIdx.x;
    int v = (tid < nb) ? bsum[tid] : 0;
    buf[tid] = v;
    __syncthreads();
    for (int off = 1; off < 128; off <<= 1) {
        int y = (tid >= off) ? buf[tid - off] : 0;
        __syncthreads();
        buf[tid] += y;
        __syncthreads();
    }
    if (tid < nb) bsum[tid] = buf[tid] - v;
    if (tid == nb - 1) bsum[nb] = buf[tid];        // grand total (padded E)
}

__global__ __launch_bounds__(SCAN_B) void scan3_k(int* __restrict__ rowptr,
                                                  const int* __restrict__ bsum,
                                                  int* __restrict__ cursor, int n, int nb) {
    int i = blockIdx.x * SCAN_B + threadIdx.x;
    if (i < n) {
        int v = rowptr[i] + bsum[blockIdx.x];
        rowptr[i] = v;
        cursor[i] = v;
    }
    if (i == 0) rowptr[n] = bsum[nb];
}

__global__ void scatter_k(const int* __restrict__ row, const int* __restrict__ col,
                          const float* __restrict__ val, int* __restrict__ cursor,
                          int2* __restrict__ ecv, int E) {
    int e = blockIdx.x * blockDim.x + threadIdx.x;
    if (e < E) {
        int r = row[e];
        int p = atomicAdd(&cursor[r], 1);
        ecv[p] = make_int2(col[e], __float_as_int(val[e]));
    }
}

// ------- weight prep: W[K][M] f32 -> Bhl[M][2K] bf16, hi8|lo8 groups -------

__global__ void split_w_k(const float* __restrict__ W, short* __restrict__ Bhl,
                          int K, int M) {
    int i = blockIdx.x * 256 + threadIdx.x;
    if (i >= K * M) return;
    int k = i / M, m = i - k * M;
    float x = W[i];
    short hi = bf16_hi(x);
    float r = x - bf16_f32(hi);
    short lo = bf16_hi(r);
    int g = k >> 3, j = k & 7;
    Bhl[(size_t)m * (2 * K) + 16 * g + j] = hi;
    Bhl[(size_t)m * (2 * K) + 16 * g + 8 + j] = lo;
}

// ---------------- unified split-MFMA GEMM with fused int16 quant -----------
// C[N,BN] = A[N,K] * B[K,BN]. 4 waves arranged NWR x NWC; wave tile =
// 64 rows x (BN/NWC) cols; per-wave frags m=4, n=NF. LDS rows 128B = 8
// 16B slots, phys_slot = logical_slot ^ (row&7).
// AF32=false: A pre-split interleaved [row][2K] (gload, pre-swizzled source).
// AF32=true (NWR must be 1): A f32 [row][K], reg-staged, converted at stage.

template <int K, int BN, int NWR, int NWC, bool AF32>
__global__ __launch_bounds__(256) void gemm_hl(const void* __restrict__ Av,
                                               const short* __restrict__ Bhl,
                                               short* __restrict__ ZQ,
                                               float* __restrict__ scl, int N) {
    constexpr int BM = 64 * NWR;
    constexpr int NF = BN / NWC / 16;
    __shared__ short Ald[BM * 64];
    __shared__ short Bld[BN * 64];

    const int tid = threadIdx.x, lane = tid & 63, w = tid >> 6;
    const int wr = w / NWC, wc = w % NWC;
    const int row0 = blockIdx.x * BM;
    const int l8 = lane >> 3;                       // row within 8-row chunk
    const int sx = (lane & 7) ^ l8;                 // pre-swizzled source slot

    f32x4 acc[4][NF] = {};

    for (int k0 = 0; k0 < K; k0 += 32) {
        // ---- stage A ----
        if constexpr (AF32) {
            const float* A = (const float*)Av;
            int row = tid >> 2, q = tid & 3;        // row 0..63, k-group q
            int gr = row0 + row;
            float4 x0 = make_float4(0.f, 0.f, 0.f, 0.f), x1 = x0;
            if (gr < N) {
                x0 = *(const float4*)&A[(size_t)gr * K + k0 + q * 8];
                x1 = *(const float4*)&A[(size_t)gr * K + k0 + q * 8 + 4];
            }
            float f[8] = {x0.x, x0.y, x0.z, x0.w, x1.x, x1.y, x1.z, x1.w};
            short8_t hi, lo;
#pragma unroll
            for (int j = 0; j < 8; ++j) {
                short hh = bf16_hi(f[j]);
                hi[j] = hh;
                lo[j] = bf16_hi(f[j] - bf16_f32(hh));
            }
            int key = row & 7;
            *(short8_t*)&Ald[row * 64 + ((2 * q) ^ key) * 8] = hi;
            *(short8_t*)&Ald[row * 64 + ((2 * q + 1) ^ key) * 8] = lo;
        } else {
            const short* Ahl = (const short*)Av;
            for (int ch = w; ch < BM / 8; ch += 4)
                gload_lds16(Ahl + (size_t)(row0 + ch * 8 + l8) * (2 * K) + 2 * k0 + sx * 8,
                            &Ald[ch * 512]);
        }
        // ---- stage B ----
        for (int ch = w; ch < BN / 8; ch += 4)
            gload_lds16(Bhl + (size_t)(ch * 8 + l8) * (2 * K) + 2 * k0 + sx * 8,
                        &Bld[ch * 512]);
        __syncthreads();

        // ---- fragments + MFMA ----
        const int sH = (lane >> 4) * 2, sL = sH + 1;   // hi/lo logical slots
        short8_t ah[4], al[4];
#pragma unroll
        for (int m = 0; m < 4; ++m) {
            int rl = wr * 64 + m * 16 + (lane & 15);
            int key = rl & 7;
            ah[m] = *(const short8_t*)&Ald[rl * 64 + (sH ^ key) * 8];
            al[m] = *(const short8_t*)&Ald[rl * 64 + (sL ^ key) * 8];
        }
#pragma unroll
        for (int n = 0; n < NF; ++n) {
            int cl = wc * (BN / NWC) + n * 16 + (lane & 15);
            int key = cl & 7;
            short8_t bh = *(const short8_t*)&Bld[cl * 64 + (sH ^ key) * 8];
            short8_t bl = *(const short8_t*)&Bld[cl * 64 + (sL ^ key) * 8];
#pragma unroll
            for (int m = 0; m < 4; ++m) {
                acc[m][n] = __builtin_amdgcn_mfma_f32_16x16x32_bf16(ah[m], bh, acc[m][n], 0, 0, 0);
                acc[m][n] = __builtin_amdgcn_mfma_f32_16x16x32_bf16(ah[m], bl, acc[m][n], 0, 0, 0);
                acc[m][n] = __builtin_amdgcn_mfma_f32_16x16x32_bf16(al[m], bh, acc[m][n], 0, 0, 0);
            }
        }
        __syncthreads();
    }

    // ---- fused quant epilogue ----
    const int lg = lane >> 4, lc = lane & 15;
    float* maxb = (float*)Ald;          // reuse LDS, post-barrier
    float rmax[4][4];
#pragma unroll
    for (int m = 0; m < 4; ++m)
#pragma unroll
        for (int r = 0; r < 4; ++r) {
            float v = 0.f;
#pragma unroll
            for (int n = 0; n < NF; ++n) v = fmaxf(v, fabsf(acc[m][n][r]));
#pragma unroll
            for (int o = 8; o >= 1; o >>= 1) v = fmaxf(v, __shfl_xor(v, o));
            rmax[m][r] = v;
        }
    if constexpr (NWC > 1) {
        if (lc == 0)
#pragma unroll
            for (int m = 0; m < 4; ++m)
#pragma unroll
                for (int r = 0; r < 4; ++r)
                    maxb[(wr * 64 + m * 16 + lg * 4 + r) * NWC + wc] = rmax[m][r];
        __syncthreads();
    }
#pragma unroll
    for (int m = 0; m < 4; ++m)
#pragma unroll
        for (int r = 0; r < 4; ++r) {
            int rl = wr * 64 + m * 16 + lg * 4 + r;
            float v = rmax[m][r];
            if constexpr (NWC > 1) {
                v = maxb[rl * NWC];
#pragma unroll
                for (int q = 1; q < NWC; ++q) v = fmaxf(v, maxb[rl * NWC + q]);
            }
            int grow = row0 + rl;
            if (grow < N) {
                float inv = (v > 0.f) ? 32767.f / v : 0.f;
                if (lc == 0 && wc == 0) scl[grow] = v * (1.f / 32767.f);
#pragma unroll
                for (int n = 0; n < NF; ++n)
                    ZQ[(size_t)grow * BN + wc * (BN / NWC) + n * 16 + lc] =
                        (short)rintf(acc[m][n][r] * inv);
            }
        }
}

// ---------------- SpMM (CSR, padded rows), one wave per dest row -----------

// d=256: 4 gathers of short4 in flight; relu; writes interleaved bf16 hi/lo.
__global__ __launch_bounds__(256) void spmm_agg256_k(const int* __restrict__ rowptr,
                                                     const int2* __restrict__ ecv,
                                                     const short* __restrict__ Q,
                                                     const float* __restrict__ scl,
                                                     short* __restrict__ Zhl, int N) {
    int row = blockIdx.x * 4 + (threadIdx.x >> 6);
    if (row >= N) return;
    int lane = threadIdx.x & 63;
    int s = rowptr[row], e = rowptr[row + 1];   // both %4
    const short4_t* Qv = (const short4_t*)Q;
    f32x4 acc = {0.f, 0.f, 0.f, 0.f};
    for (int i = s; i < e; i += 4) {
        int4 a = *(const int4*)(ecv + i);
        int4 b = *(const int4*)(ecv + i + 2);
        float w0 = __int_as_float(a.y) * scl[a.x];
        float w1 = __int_as_float(a.w) * scl[a.z];
        float w2 = __int_as_float(b.y) * scl[b.x];
        float w3 = __int_as_float(b.w) * scl[b.z];
        short4_t q0 = Qv[(size_t)a.x * 64 + lane];
        short4_t q1 = Qv[(size_t)a.z * 64 + lane];
        short4_t q2 = Qv[(size_t)b.x * 64 + lane];
        short4_t q3 = Qv[(size_t)b.z * 64 + lane];
#pragma unroll
        for (int j = 0; j < 4; ++j) {
            acc[j] = fmaf(w0, (float)q0[j], acc[j]);
            acc[j] = fmaf(w1, (float)q1[j], acc[j]);
            acc[j] = fmaf(w2, (float)q2[j], acc[j]);
            acc[j] = fmaf(w3, (float)q3[j], acc[j]);
        }
    }
    // relu + hi/lo split, interleaved layout: group g = lane>>1, half = lane&1
    short4_t hi, lo;
#pragma unroll
    for (int j = 0; j < 4; ++j) {
        float r = fmaxf(acc[j], 0.f);
        short h = bf16_hi(r);
        hi[j] = h;
        lo[j] = bf16_hi(r - bf16_f32(h));
    }
    size_t base = (size_t)row * 512 + (lane >> 1) * 16 + (lane & 1) * 4;
    *(short4_t*)&Zhl[base] = hi;
    *(short4_t*)&Zhl[base + 8] = lo;
}

// d=64: 4 gathers of short in flight; fused row softmax.
__global__ __launch_bounds__(256) void spmm_softmax64_k(const int* __restrict__ rowptr,
                                                        const int2* __restrict__ ecv,
                                                        const short* __restrict__ Q,
                                                        const float* __restrict__ scl,
                                                        float* __restrict__ out, int N) {
    int row = blockIdx.x * 4 + (threadIdx.x >> 6);
    if (row >= N) return;
    int lane = threadIdx.x & 63;
    int s = rowptr[row], e = rowptr[row + 1];
    float acc = 0.f;
    for (int i = s; i < e; i += 4) {
        int4 a = *(const int4*)(ecv + i);
        int4 b = *(const int4*)(ecv + i + 2);
        float w0 = __int_as_float(a.y) * scl[a.x];
        float w1 = __int_as_float(a.w) * scl[a.z];
        float w2 = __int_as_float(b.y) * scl[b.x];
        float w3 = __int_as_float(b.w) * scl[b.z];
        float z0 = (float)Q[(size_t)a.x * 64 + lane];
        float z1 = (float)Q[(size_t)a.z * 64 + lane];
        float z2 = (float)Q[(size_t)b.x * 64 + lane];
        float z3 = (float)Q[(size_t)b.z * 64 + lane];
        acc = fmaf(w0, z0, acc);
        acc = fmaf(w1, z1, acc);
        acc = fmaf(w2, z2, acc);
        acc = fmaf(w3, z3, acc);
    }
    float m = acc;
#pragma unroll
    for (int o = 32; o >= 1; o >>= 1) m = fmaxf(m, __shfl_xor(m, o));
    float p = __expf(acc - m);
    float ssum = p;
#pragma unroll
    for (int o = 32; o >= 1; o >>= 1) ssum += __shfl_xor(ssum, o);
    out[(size_t)row * 64 + lane] = p / ssum;
}

// ---------------------------------------------------------------------------

extern "C" void kernel_launch(void* const* d_in, const int* in_sizes, int n_in,
                              void* d_out, int out_size, void* d_ws, size_t ws_size,
                              hipStream_t stream) {
    const float* X        = (const float*)d_in[0];
    const int*   edge_row = (const int*)d_in[1];
    const int*   edge_col = (const int*)d_in[2];
    const float* edge_val = (const float*)d_in[3];
    const float* W0       = (const float*)d_in[4];
    const float* Wh1      = (const float*)d_in[5];
    const float* W1       = (const float*)d_in[6];

    const int C = 512, H = 256, F = 64;
    const int N = in_sizes[0] / C;     // 100000
    const int E = in_sizes[1];         // 3200000
    const int EPAD = E + 4 * N + 64;   // padded-edge capacity

    size_t off = 0;
    auto alloc = [&](size_t bytes) -> void* {
        void* p = (char*)d_ws + off;
        off += (bytes + 255) & ~(size_t)255;
        return p;
    };
    // Zhl first: gemm_hl gload-A overreads it by <=127 rows (128KB);
    // ZQ follows as slack.
    short* Zhl    = (short*)alloc((size_t)N * 2 * H * sizeof(short));  // 102.4MB
    short* ZQ     = (short*)alloc((size_t)N * H * sizeof(short));      // 51.2MB
    float* scl    = (float*)alloc((size_t)N * sizeof(float));
    int*   deg    = (int*)alloc((size_t)N * sizeof(int));
    int*   rowptr = (int*)alloc((size_t)(N + 1) * sizeof(int));
    int*   cursor = (int*)alloc((size_t)N * sizeof(int));
    int*   bsum   = (int*)alloc(129 * sizeof(int));
    int2*  ecv    = (int2*)alloc((size_t)EPAD * sizeof(int2));
    short* Bhl0   = (short*)alloc((size_t)H * 2 * C * sizeof(short));  // [256][1024]
    short* Bhl1   = (short*)alloc((size_t)H * 2 * H * sizeof(short));  // [256][512]
    short* Bhl2   = (short*)alloc((size_t)F * 2 * H * sizeof(short));  // [64][512]
    (void)ws_size;

    // ---- build padded CSR ----
    hipMemsetAsync(deg, 0, (size_t)N * sizeof(int), stream);
    hipMemsetAsync(ecv, 0, (size_t)EPAD * sizeof(int2), stream);
    count_rows_k<<<(E + 255) / 256, 256, 0, stream>>>(edge_row, deg, E);
    int nb = (N + SCAN_B - 1) / SCAN_B;          // 98 <= 128
    scan1_k<<<nb, SCAN_B, 0, stream>>>(deg, rowptr, bsum, N);
    scan2_k<<<1, 128, 0, stream>>>(bsum, nb);
    scan3_k<<<nb, SCAN_B, 0, stream>>>(rowptr, bsum, cursor, N, nb);
    scatter_k<<<(E + 255) / 256, 256, 0, stream>>>(edge_row, edge_col, edge_val,
                                                   cursor, ecv, E);

    // ---- prep weights ----
    split_w_k<<<(C * H + 255) / 256, 256, 0, stream>>>(W0, Bhl0, C, H);
    split_w_k<<<(H * H + 255) / 256, 256, 0, stream>>>(Wh1, Bhl1, H, H);
    split_w_k<<<(H * F + 255) / 256, 256, 0, stream>>>(W1, Bhl2, H, F);

    const int g64  = (N + 63) / 64;              // 1563
    const int g128 = (N + 127) / 128;            // 782
    const int rg   = (N + 3) / 4;                // 25000

    // ---- layer 0 ----
    gemm_hl<512, 256, 1, 4, true><<<g64, 256, 0, stream>>>(X, Bhl0, ZQ, scl, N);
    spmm_agg256_k<<<rg, 256, 0, stream>>>(rowptr, ecv, ZQ, scl, Zhl, N);
    // ---- layer 1 ----
    gemm_hl<256, 256, 1, 4, false><<<g64, 256, 0, stream>>>(Zhl, Bhl1, ZQ, scl, N);
    spmm_agg256_k<<<rg, 256, 0, stream>>>(rowptr, ecv, ZQ, scl, Zhl, N);
    // ---- layer 2 ----
    gemm_hl<256, 64, 2, 2, false><<<g128, 256, 0, stream>>>(Zhl, Bhl2, ZQ, scl, N);
    spmm_softmax64_k<<<rg, 256, 0, stream>>>(rowptr, ecv, ZQ, scl,
                                             (float*)d_out, N);
}